// Round 1
// baseline (1052.388 us; speedup 1.0000x reference)
//
#include <hip/hip_runtime.h>
#include <hip/hip_bf16.h>

// ---------------- preprocessing ----------------

__global__ __launch_bounds__(256) void k_count(const int* __restrict__ dst, int E,
                                               int* __restrict__ cnt) {
    int e = blockIdx.x * 256 + threadIdx.x;
    if (e < E) atomicAdd(&cnt[dst[e]], 1);
}

// chunk = 1024 elements per block, thread t owns elements [t*4, t*4+4)
__global__ __launch_bounds__(256) void k_scan1(const int* __restrict__ cnt, int N,
                                               int* __restrict__ part) {
    __shared__ int sh[256];
    int base = blockIdx.x * 1024;
    int t = threadIdx.x;
    int s = 0;
#pragma unroll
    for (int i = 0; i < 4; i++) {
        int idx = base + t * 4 + i;
        if (idx < N) s += cnt[idx];
    }
    sh[t] = s;
    __syncthreads();
    for (int off = 128; off > 0; off >>= 1) {
        if (t < off) sh[t] += sh[t + off];
        __syncthreads();
    }
    if (t == 0) part[blockIdx.x] = sh[0];
}

__global__ __launch_bounds__(1024) void k_scan2(const int* __restrict__ part,
                                                int* __restrict__ boff, int nblk,
                                                int* __restrict__ rowstart, int N, int E) {
    __shared__ int sh[1024];
    int t = threadIdx.x;
    int v = (t < nblk) ? part[t] : 0;
    sh[t] = v;
    __syncthreads();
    for (int off = 1; off < 1024; off <<= 1) {
        int x = (t >= off) ? sh[t - off] : 0;
        __syncthreads();
        sh[t] += x;
        __syncthreads();
    }
    if (t < nblk) boff[t] = sh[t] - v;  // exclusive
    if (t == 0) rowstart[N] = E;
}

__global__ __launch_bounds__(256) void k_scan3(const int* __restrict__ cnt, int N,
                                               const int* __restrict__ boff,
                                               int* __restrict__ rowstart) {
    __shared__ int sh[256];
    int base = blockIdx.x * 1024;
    int t = threadIdx.x;
    int idx = base + t * 4;
    int v0 = 0, v1 = 0, v2 = 0, v3 = 0;
    if (idx + 3 < N) {
        int4 q = *(const int4*)&cnt[idx];
        v0 = q.x; v1 = q.y; v2 = q.z; v3 = q.w;
    } else {
        if (idx < N) v0 = cnt[idx];
        if (idx + 1 < N) v1 = cnt[idx + 1];
        if (idx + 2 < N) v2 = cnt[idx + 2];
        if (idx + 3 < N) v3 = cnt[idx + 3];
    }
    int tot = v0 + v1 + v2 + v3;
    sh[t] = tot;
    __syncthreads();
    for (int off = 1; off < 256; off <<= 1) {
        int x = (t >= off) ? sh[t - off] : 0;
        __syncthreads();
        sh[t] += x;
        __syncthreads();
    }
    int excl = sh[t] - tot;
    int b0 = boff[blockIdx.x] + excl;
    if (idx + 3 < N) {
        int4 w = make_int4(b0, b0 + v0, b0 + v0 + v1, b0 + v0 + v1 + v2);
        *(int4*)&rowstart[idx] = w;
    } else {
        if (idx < N) rowstart[idx] = b0;
        if (idx + 1 < N) rowstart[idx + 1] = b0 + v0;
        if (idx + 2 < N) rowstart[idx + 2] = b0 + v0 + v1;
        if (idx + 3 < N) rowstart[idx + 3] = b0 + v0 + v1 + v2;
    }
}

__global__ __launch_bounds__(256) void k_dinv(const int* __restrict__ cnt,
                                              float* __restrict__ dinv, int N) {
    int n = blockIdx.x * 256 + threadIdx.x;
    if (n < N) dinv[n] = rsqrtf((float)cnt[n] + 1.0f);  // deg = in-edges + self-loop
}

__global__ __launch_bounds__(256) void k_fill(const int* __restrict__ src,
                                              const int* __restrict__ dst, int E,
                                              const int* __restrict__ rowstart,
                                              int* __restrict__ cursor,
                                              const float* __restrict__ dinv,
                                              int* __restrict__ csr_src,
                                              float* __restrict__ csr_norm) {
    int e = blockIdx.x * 256 + threadIdx.x;
    if (e >= E) return;
    int s = src[e], d = dst[e];
    int pos = rowstart[d] + atomicAdd(&cursor[d], 1);
    csr_src[pos] = s;
    csr_norm[pos] = dinv[s] * dinv[d];
}

// ---------------- GEMM: T = A @ W  (A:[N,128] f32, W:[128,128]) ----------------
// 128-row x 128-col tile per block, 256 threads, 8x8 per thread, K in chunks of 32.

__global__ __launch_bounds__(256) void k_gemm(const float* __restrict__ A,
                                              const float* __restrict__ W,
                                              float* __restrict__ T, int N) {
    __shared__ float AshT[32][132];  // [k][row], pad 132 for transpose-store
    __shared__ float Wsh[32][132];   // [k][col]
    int t = threadIdx.x;
    int tr = t >> 4;        // 0..15
    int tc = t & 15;        // 0..15
    int rowBase = blockIdx.x * 128;
    float acc[8][8] = {};

    for (int kc = 0; kc < 4; kc++) {
#pragma unroll
        for (int i = 0; i < 4; i++) {
            int q = t + i * 256;     // float4 id, 0..1023
            int row = q >> 3;        // 0..127
            int c4 = q & 7;          // 0..7
            int gr = rowBase + row;
            float4 a4 = make_float4(0.f, 0.f, 0.f, 0.f);
            if (gr < N) a4 = *(const float4*)&A[(size_t)gr * 128 + kc * 32 + c4 * 4];
            AshT[c4 * 4 + 0][row] = a4.x;
            AshT[c4 * 4 + 1][row] = a4.y;
            AshT[c4 * 4 + 2][row] = a4.z;
            AshT[c4 * 4 + 3][row] = a4.w;
        }
#pragma unroll
        for (int i = 0; i < 4; i++) {
            int q = t + i * 256;     // 0..1023
            int k = q >> 5;          // 0..31
            int c4 = q & 31;         // 0..31
            float4 w4 = *(const float4*)&W[(size_t)(kc * 32 + k) * 128 + c4 * 4];
            *(float4*)&Wsh[k][c4 * 4] = w4;
        }
        __syncthreads();
#pragma unroll
        for (int k = 0; k < 32; k++) {
            float4 a0 = *(const float4*)&AshT[k][tr * 8];
            float4 a1 = *(const float4*)&AshT[k][tr * 8 + 4];
            float4 w0 = *(const float4*)&Wsh[k][tc * 8];
            float4 w1 = *(const float4*)&Wsh[k][tc * 8 + 4];
            float a[8] = {a0.x, a0.y, a0.z, a0.w, a1.x, a1.y, a1.z, a1.w};
            float w[8] = {w0.x, w0.y, w0.z, w0.w, w1.x, w1.y, w1.z, w1.w};
#pragma unroll
            for (int i = 0; i < 8; i++)
#pragma unroll
                for (int j = 0; j < 8; j++) acc[i][j] = fmaf(a[i], w[j], acc[i][j]);
        }
        __syncthreads();
    }
#pragma unroll
    for (int i = 0; i < 8; i++) {
        int gr = rowBase + tr * 8 + i;
        if (gr < N) {
            *(float4*)&T[(size_t)gr * 128 + tc * 8] =
                make_float4(acc[i][0], acc[i][1], acc[i][2], acc[i][3]);
            *(float4*)&T[(size_t)gr * 128 + tc * 8 + 4] =
                make_float4(acc[i][4], acc[i][5], acc[i][6], acc[i][7]);
        }
    }
}

// ---------------- aggregation: H[n] = relu(sum + b) (+ H[n] if RES) ----------------
// one block (128 threads) per node; self-loop handled analytically.

template <int RES>
__global__ __launch_bounds__(128) void k_agg(const float* __restrict__ T,
                                             const int* __restrict__ rowstart,
                                             const int* __restrict__ csr_src,
                                             const float* __restrict__ csr_norm,
                                             const float* __restrict__ dinv,
                                             const float* __restrict__ bias,
                                             float* __restrict__ H, int N) {
    int n = blockIdx.x;
    int c = threadIdx.x;
    float dn = dinv[n];
    float acc = T[(size_t)n * 128 + c] * dn * dn;  // self-loop, norm = dinv[n]^2
    int e0 = rowstart[n], e1 = rowstart[n + 1];
    for (int e = e0; e < e1; e++) {
        int s = csr_src[e];
        float w = csr_norm[e];
        acc = fmaf(T[(size_t)s * 128 + c], w, acc);
    }
    float v = fmaxf(acc + bias[c], 0.0f);
    if (RES)
        H[(size_t)n * 128 + c] = v + H[(size_t)n * 128 + c];
    else
        H[(size_t)n * 128 + c] = v;
}

// ---------------- pooling ----------------

__global__ __launch_bounds__(256) void k_gstart(const int* __restrict__ batch, int N, int G,
                                                int* __restrict__ gstart) {
    int g = blockIdx.x * 256 + threadIdx.x;
    if (g > G) return;
    if (g == G) { gstart[g] = N; return; }
    int lo = 0, hi = N;
    while (lo < hi) {
        int mid = (lo + hi) >> 1;
        if (batch[mid] < g) lo = mid + 1; else hi = mid;
    }
    gstart[g] = lo;
}

__global__ __launch_bounds__(128) void k_pool(const float* __restrict__ H,
                                              const int* __restrict__ gstart,
                                              float* __restrict__ gfeat) {
    int g = blockIdx.x;
    int c = threadIdx.x;
    int i0 = gstart[g], i1 = gstart[g + 1];
    float s = 0.f, m = -3.4e38f;
    for (int i = i0; i < i1; i++) {
        float v = H[(size_t)i * 128 + c];
        s += v;
        m = fmaxf(m, v);
    }
    int cn = i1 - i0;
    float mean = (cn > 0) ? s / (float)cn : 0.f;
    if (cn == 0) m = 0.f;
    gfeat[g * 256 + c] = mean;
    gfeat[g * 256 + 128 + c] = m;
}

// ---------------- MLP head ----------------

__global__ __launch_bounds__(128) void k_mlp(const float* __restrict__ gfeat,
                                             const float* __restrict__ Wf1,
                                             const float* __restrict__ bf1,
                                             const float* __restrict__ Wf2,
                                             const float* __restrict__ bf2,
                                             const float* __restrict__ Wf3,
                                             const float* __restrict__ bf3,
                                             float* __restrict__ out) {
    __shared__ float grow[256];
    __shared__ float o1[128];
    __shared__ float o2[64];
    int g = blockIdx.x;
    int t = threadIdx.x;
    grow[t] = gfeat[g * 256 + t];
    grow[t + 128] = gfeat[g * 256 + 128 + t];
    __syncthreads();
    float acc = bf1[t];
#pragma unroll 8
    for (int k = 0; k < 256; k++) acc = fmaf(grow[k], Wf1[k * 128 + t], acc);
    o1[t] = fmaxf(acc, 0.f);
    __syncthreads();
    if (t < 64) {
        float a2 = bf2[t];
#pragma unroll 8
        for (int k = 0; k < 128; k++) a2 = fmaf(o1[k], Wf2[k * 64 + t], a2);
        o2[t] = fmaxf(a2, 0.f);
    }
    __syncthreads();
    if (t < 64) {
        float p = o2[t] * Wf3[t];
        for (int off = 32; off > 0; off >>= 1) p += __shfl_down(p, off);
        if (t == 0) out[g] = p + bf3[0];
    }
}

// ---------------- launch ----------------

extern "C" void kernel_launch(void* const* d_in, const int* in_sizes, int n_in,
                              void* d_out, int out_size, void* d_ws, size_t ws_size,
                              hipStream_t stream) {
    const float* x = (const float*)d_in[0];
    const int* ei = (const int*)d_in[1];
    const int* batch = (const int*)d_in[2];
    // d_in[3] = n_graphs (device scalar); G == out_size since output is [G,1]
    const float* W1 = (const float*)d_in[4];
    const float* b1 = (const float*)d_in[5];
    const float* W2 = (const float*)d_in[6];
    const float* b2 = (const float*)d_in[7];
    const float* W3 = (const float*)d_in[8];
    const float* b3 = (const float*)d_in[9];
    const float* Wf1 = (const float*)d_in[10];
    const float* bf1 = (const float*)d_in[11];
    const float* Wf2 = (const float*)d_in[12];
    const float* bf2 = (const float*)d_in[13];
    const float* Wf3 = (const float*)d_in[14];
    const float* bf3 = (const float*)d_in[15];

    const int N = in_sizes[0] / 128;
    const int E = in_sizes[1] / 2;
    const int G = out_size;

    const int* src = ei;
    const int* dst = ei + E;

    // workspace carve (256B aligned)
    char* w = (char*)d_ws;
    size_t off = 0;
    auto alloc = [&](size_t bytes) -> void* {
        void* p = w + off;
        off += (bytes + 255) / 256 * 256;
        return p;
    };
    float* T = (float*)alloc((size_t)N * 128 * 4);
    float* H = (float*)alloc((size_t)N * 128 * 4);
    int* csr_src = (int*)alloc((size_t)E * 4);
    float* csr_norm = (float*)alloc((size_t)E * 4);
    int* rowstart = (int*)alloc((size_t)(N + 1) * 4);
    int* cnt = (int*)alloc((size_t)N * 4);
    int* cursor = (int*)alloc((size_t)N * 4);
    float* dinv = (float*)alloc((size_t)N * 4);
    int* part = (int*)alloc(1024 * 4);
    int* boff = (int*)alloc(1024 * 4);
    int* gstart = (int*)alloc((size_t)(G + 1) * 4);
    float* gfeat = (float*)alloc((size_t)G * 256 * 4);
    float* out = (float*)d_out;

    const int nblk = (N + 1023) / 1024;

    hipMemsetAsync(cnt, 0, (size_t)N * 4, stream);
    hipMemsetAsync(cursor, 0, (size_t)N * 4, stream);

    k_count<<<dim3((E + 255) / 256), dim3(256), 0, stream>>>(dst, E, cnt);
    k_scan1<<<dim3(nblk), dim3(256), 0, stream>>>(cnt, N, part);
    k_scan2<<<dim3(1), dim3(1024), 0, stream>>>(part, boff, nblk, rowstart, N, E);
    k_scan3<<<dim3(nblk), dim3(256), 0, stream>>>(cnt, N, boff, rowstart);
    k_dinv<<<dim3((N + 255) / 256), dim3(256), 0, stream>>>(cnt, dinv, N);
    k_fill<<<dim3((E + 255) / 256), dim3(256), 0, stream>>>(src, dst, E, rowstart, cursor,
                                                            dinv, csr_src, csr_norm);

    const int gemmGrid = (N + 127) / 128;

    // conv1: H = relu(agg(x @ W1) + b1)
    k_gemm<<<dim3(gemmGrid), dim3(256), 0, stream>>>(x, W1, T, N);
    k_agg<0><<<dim3(N), dim3(128), 0, stream>>>(T, rowstart, csr_src, csr_norm, dinv, b1, H, N);

    // conv2: H = relu(agg(H @ W2) + b2) + H
    k_gemm<<<dim3(gemmGrid), dim3(256), 0, stream>>>(H, W2, T, N);
    k_agg<1><<<dim3(N), dim3(128), 0, stream>>>(T, rowstart, csr_src, csr_norm, dinv, b2, H, N);

    // conv3: H = relu(agg(H @ W3) + b3) + H
    k_gemm<<<dim3(gemmGrid), dim3(256), 0, stream>>>(H, W3, T, N);
    k_agg<1><<<dim3(N), dim3(128), 0, stream>>>(T, rowstart, csr_src, csr_norm, dinv, b3, H, N);

    // pooling + head
    k_gstart<<<dim3((G + 256) / 256), dim3(256), 0, stream>>>(batch, N, G, gstart);
    k_pool<<<dim3(G), dim3(128), 0, stream>>>(H, gstart, gfeat);
    k_mlp<<<dim3(G), dim3(128), 0, stream>>>(gfeat, Wf1, bf1, Wf2, bf2, Wf3, bf3, out);
}

// Round 2
// 905.190 us; speedup vs baseline: 1.1626x; 1.1626x over previous
//
#include <hip/hip_runtime.h>
#include <hip/hip_bf16.h>

// ---------------- preprocessing ----------------

__global__ __launch_bounds__(256) void k_count(const int* __restrict__ dst, int E,
                                               int* __restrict__ cnt) {
    int e = blockIdx.x * 256 + threadIdx.x;
    if (e < E) atomicAdd(&cnt[dst[e]], 1);
}

// chunk = 1024 elements per block, thread t owns elements [t*4, t*4+4)
__global__ __launch_bounds__(256) void k_scan1(const int* __restrict__ cnt, int N,
                                               int* __restrict__ part) {
    __shared__ int sh[256];
    int base = blockIdx.x * 1024;
    int t = threadIdx.x;
    int s = 0;
#pragma unroll
    for (int i = 0; i < 4; i++) {
        int idx = base + t * 4 + i;
        if (idx < N) s += cnt[idx];
    }
    sh[t] = s;
    __syncthreads();
    for (int off = 128; off > 0; off >>= 1) {
        if (t < off) sh[t] += sh[t + off];
        __syncthreads();
    }
    if (t == 0) part[blockIdx.x] = sh[0];
}

__global__ __launch_bounds__(1024) void k_scan2(const int* __restrict__ part,
                                                int* __restrict__ boff, int nblk,
                                                int* __restrict__ rowstart, int N, int E) {
    __shared__ int sh[1024];
    int t = threadIdx.x;
    int v = (t < nblk) ? part[t] : 0;
    sh[t] = v;
    __syncthreads();
    for (int off = 1; off < 1024; off <<= 1) {
        int x = (t >= off) ? sh[t - off] : 0;
        __syncthreads();
        sh[t] += x;
        __syncthreads();
    }
    if (t < nblk) boff[t] = sh[t] - v;  // exclusive
    if (t == 0) rowstart[N] = E;
}

__global__ __launch_bounds__(256) void k_scan3(const int* __restrict__ cnt, int N,
                                               const int* __restrict__ boff,
                                               int* __restrict__ rowstart) {
    __shared__ int sh[256];
    int base = blockIdx.x * 1024;
    int t = threadIdx.x;
    int idx = base + t * 4;
    int v0 = 0, v1 = 0, v2 = 0, v3 = 0;
    if (idx + 3 < N) {
        int4 q = *(const int4*)&cnt[idx];
        v0 = q.x; v1 = q.y; v2 = q.z; v3 = q.w;
    } else {
        if (idx < N) v0 = cnt[idx];
        if (idx + 1 < N) v1 = cnt[idx + 1];
        if (idx + 2 < N) v2 = cnt[idx + 2];
        if (idx + 3 < N) v3 = cnt[idx + 3];
    }
    int tot = v0 + v1 + v2 + v3;
    sh[t] = tot;
    __syncthreads();
    for (int off = 1; off < 256; off <<= 1) {
        int x = (t >= off) ? sh[t - off] : 0;
        __syncthreads();
        sh[t] += x;
        __syncthreads();
    }
    int excl = sh[t] - tot;
    int b0 = boff[blockIdx.x] + excl;
    if (idx + 3 < N) {
        int4 w = make_int4(b0, b0 + v0, b0 + v0 + v1, b0 + v0 + v1 + v2);
        *(int4*)&rowstart[idx] = w;
    } else {
        if (idx < N) rowstart[idx] = b0;
        if (idx + 1 < N) rowstart[idx + 1] = b0 + v0;
        if (idx + 2 < N) rowstart[idx + 2] = b0 + v0 + v1;
        if (idx + 3 < N) rowstart[idx + 3] = b0 + v0 + v1 + v2;
    }
}

__global__ __launch_bounds__(256) void k_dinv(const int* __restrict__ cnt,
                                              float* __restrict__ dinv, int N) {
    int n = blockIdx.x * 256 + threadIdx.x;
    if (n < N) dinv[n] = rsqrtf((float)cnt[n] + 1.0f);  // deg = in-edges + self-loop
}

__global__ __launch_bounds__(256) void k_fill(const int* __restrict__ src,
                                              const int* __restrict__ dst, int E,
                                              const int* __restrict__ rowstart,
                                              int* __restrict__ cursor,
                                              int* __restrict__ csr_src) {
    int e = blockIdx.x * 256 + threadIdx.x;
    if (e >= E) return;
    int s = src[e], d = dst[e];
    int pos = rowstart[d] + atomicAdd(&cursor[d], 1);
    csr_src[pos] = s;
}

// ---------------- GEMM: U = dinv .* (A @ W)  (A:[N,128] f32, W:[128,128]) -------
// 128-row x 128-col tile per block, 256 threads, 8x8 per thread, K in chunks of 32.
// Epilogue scales row r by dinv[r] so the aggregation needs no per-edge weight:
//   sum_e dinv_s*dinv_d*T_s = dinv_d * sum_e U_s,  U = dinv .* T.

__global__ __launch_bounds__(256) void k_gemm(const float* __restrict__ A,
                                              const float* __restrict__ W,
                                              const float* __restrict__ dinv,
                                              float* __restrict__ U, int N) {
    __shared__ float AshT[32][132];  // [k][row], pad 132 for transpose-store
    __shared__ float Wsh[32][132];   // [k][col]
    int t = threadIdx.x;
    int tr = t >> 4;        // 0..15
    int tc = t & 15;        // 0..15
    int rowBase = blockIdx.x * 128;
    float acc[8][8] = {};

    for (int kc = 0; kc < 4; kc++) {
#pragma unroll
        for (int i = 0; i < 4; i++) {
            int q = t + i * 256;     // float4 id, 0..1023
            int row = q >> 3;        // 0..127
            int c4 = q & 7;          // 0..7
            int gr = rowBase + row;
            float4 a4 = make_float4(0.f, 0.f, 0.f, 0.f);
            if (gr < N) a4 = *(const float4*)&A[(size_t)gr * 128 + kc * 32 + c4 * 4];
            AshT[c4 * 4 + 0][row] = a4.x;
            AshT[c4 * 4 + 1][row] = a4.y;
            AshT[c4 * 4 + 2][row] = a4.z;
            AshT[c4 * 4 + 3][row] = a4.w;
        }
#pragma unroll
        for (int i = 0; i < 4; i++) {
            int q = t + i * 256;     // 0..1023
            int k = q >> 5;          // 0..31
            int c4 = q & 31;         // 0..31
            float4 w4 = *(const float4*)&W[(size_t)(kc * 32 + k) * 128 + c4 * 4];
            *(float4*)&Wsh[k][c4 * 4] = w4;
        }
        __syncthreads();
#pragma unroll
        for (int k = 0; k < 32; k++) {
            float4 a0 = *(const float4*)&AshT[k][tr * 8];
            float4 a1 = *(const float4*)&AshT[k][tr * 8 + 4];
            float4 w0 = *(const float4*)&Wsh[k][tc * 8];
            float4 w1 = *(const float4*)&Wsh[k][tc * 8 + 4];
            float a[8] = {a0.x, a0.y, a0.z, a0.w, a1.x, a1.y, a1.z, a1.w};
            float w[8] = {w0.x, w0.y, w0.z, w0.w, w1.x, w1.y, w1.z, w1.w};
#pragma unroll
            for (int i = 0; i < 8; i++)
#pragma unroll
                for (int j = 0; j < 8; j++) acc[i][j] = fmaf(a[i], w[j], acc[i][j]);
        }
        __syncthreads();
    }
#pragma unroll
    for (int i = 0; i < 8; i++) {
        int gr = rowBase + tr * 8 + i;
        if (gr < N) {
            float dv = dinv[gr];
            *(float4*)&U[(size_t)gr * 128 + tc * 8] =
                make_float4(dv * acc[i][0], dv * acc[i][1], dv * acc[i][2], dv * acc[i][3]);
            *(float4*)&U[(size_t)gr * 128 + tc * 8 + 4] =
                make_float4(dv * acc[i][4], dv * acc[i][5], dv * acc[i][6], dv * acc[i][7]);
        }
    }
}

// ---------------- aggregation ----------------
// H[n] = relu(dinv[n] * (U[n] + sum_{e in CSR(n)} U[src_e]) + bias) (+ H[n] if RES)
// One wave per node. Two 32-lane groups each gather full 512B rows as float4;
// unroll x2 => 4 independent rows in flight per wave. Combine groups via shfl_xor.

template <int RES>
__global__ __launch_bounds__(256) void k_agg(const float* __restrict__ U,
                                             const int* __restrict__ rowstart,
                                             const int* __restrict__ csr_src,
                                             const float* __restrict__ dinv,
                                             const float* __restrict__ bias,
                                             float* __restrict__ H, int N) {
    int wave = threadIdx.x >> 6;  // 0..3
    int lane = threadIdx.x & 63;
    int n = blockIdx.x * 4 + wave;
    if (n >= N) return;
    int g = lane >> 5;   // edge group 0/1
    int l = lane & 31;   // channel quad: channels l*4 .. l*4+3
    int e0 = rowstart[n], e1 = rowstart[n + 1];

    float ax = 0.f, ay = 0.f, az = 0.f, aw = 0.f;
    int e = e0 + g;
    // main loop: 2 rows per group iteration (stride 4 over shared edge list)
    for (; e + 2 < e1; e += 4) {
        int s0 = csr_src[e];
        int s1 = csr_src[e + 2];
        float4 r0 = *(const float4*)&U[(size_t)s0 * 128 + l * 4];
        float4 r1 = *(const float4*)&U[(size_t)s1 * 128 + l * 4];
        ax += r0.x + r1.x;
        ay += r0.y + r1.y;
        az += r0.z + r1.z;
        aw += r0.w + r1.w;
    }
    if (e < e1) {
        int s0 = csr_src[e];
        float4 r0 = *(const float4*)&U[(size_t)s0 * 128 + l * 4];
        ax += r0.x; ay += r0.y; az += r0.z; aw += r0.w;
    }
    // combine the two groups (xor 32 sums both halves into every lane)
    ax += __shfl_xor(ax, 32);
    ay += __shfl_xor(ay, 32);
    az += __shfl_xor(az, 32);
    aw += __shfl_xor(aw, 32);

    if (g == 0) {
        float4 self = *(const float4*)&U[(size_t)n * 128 + l * 4];
        float4 bi = *(const float4*)&bias[l * 4];
        float dn = dinv[n];
        float4 out;
        out.x = fmaxf(dn * (ax + self.x) + bi.x, 0.f);
        out.y = fmaxf(dn * (ay + self.y) + bi.y, 0.f);
        out.z = fmaxf(dn * (az + self.z) + bi.z, 0.f);
        out.w = fmaxf(dn * (aw + self.w) + bi.w, 0.f);
        if (RES) {
            float4 h = *(const float4*)&H[(size_t)n * 128 + l * 4];
            out.x += h.x; out.y += h.y; out.z += h.z; out.w += h.w;
        }
        *(float4*)&H[(size_t)n * 128 + l * 4] = out;
    }
}

// ---------------- pooling ----------------

__global__ __launch_bounds__(256) void k_gstart(const int* __restrict__ batch, int N, int G,
                                                int* __restrict__ gstart) {
    int g = blockIdx.x * 256 + threadIdx.x;
    if (g > G) return;
    if (g == G) { gstart[g] = N; return; }
    int lo = 0, hi = N;
    while (lo < hi) {
        int mid = (lo + hi) >> 1;
        if (batch[mid] < g) lo = mid + 1; else hi = mid;
    }
    gstart[g] = lo;
}

// one block (256 threads) per graph; two halves of the node range in parallel
__global__ __launch_bounds__(256) void k_pool(const float* __restrict__ H,
                                              const int* __restrict__ gstart,
                                              float* __restrict__ gfeat) {
    __shared__ float ssum[256];
    __shared__ float smax[256];
    int g = blockIdx.x;
    int c = threadIdx.x & 127;
    int half = threadIdx.x >> 7;
    int i0 = gstart[g], i1 = gstart[g + 1];
    int cn = i1 - i0;
    int mid = i0 + (cn >> 1);
    int a0 = half ? mid : i0;
    int a1 = half ? i1 : mid;
    float s = 0.f, m = -3.4e38f;
    for (int i = a0; i < a1; i++) {
        float v = H[(size_t)i * 128 + c];
        s += v;
        m = fmaxf(m, v);
    }
    ssum[threadIdx.x] = s;
    smax[threadIdx.x] = m;
    __syncthreads();
    if (half == 0) {
        float st = ssum[c] + ssum[c + 128];
        float mt = fmaxf(smax[c], smax[c + 128]);
        float mean = (cn > 0) ? st / (float)cn : 0.f;
        if (cn == 0) mt = 0.f;
        gfeat[g * 256 + c] = mean;
        gfeat[g * 256 + 128 + c] = mt;
    }
}

// ---------------- MLP head ----------------

__global__ __launch_bounds__(128) void k_mlp(const float* __restrict__ gfeat,
                                             const float* __restrict__ Wf1,
                                             const float* __restrict__ bf1,
                                             const float* __restrict__ Wf2,
                                             const float* __restrict__ bf2,
                                             const float* __restrict__ Wf3,
                                             const float* __restrict__ bf3,
                                             float* __restrict__ out) {
    __shared__ float grow[256];
    __shared__ float o1[128];
    __shared__ float o2[64];
    int g = blockIdx.x;
    int t = threadIdx.x;
    grow[t] = gfeat[g * 256 + t];
    grow[t + 128] = gfeat[g * 256 + 128 + t];
    __syncthreads();
    float acc = bf1[t];
#pragma unroll 8
    for (int k = 0; k < 256; k++) acc = fmaf(grow[k], Wf1[k * 128 + t], acc);
    o1[t] = fmaxf(acc, 0.f);
    __syncthreads();
    if (t < 64) {
        float a2 = bf2[t];
#pragma unroll 8
        for (int k = 0; k < 128; k++) a2 = fmaf(o1[k], Wf2[k * 64 + t], a2);
        o2[t] = fmaxf(a2, 0.f);
    }
    __syncthreads();
    if (t < 64) {
        float p = o2[t] * Wf3[t];
        for (int off = 32; off > 0; off >>= 1) p += __shfl_down(p, off);
        if (t == 0) out[g] = p + bf3[0];
    }
}

// ---------------- launch ----------------

extern "C" void kernel_launch(void* const* d_in, const int* in_sizes, int n_in,
                              void* d_out, int out_size, void* d_ws, size_t ws_size,
                              hipStream_t stream) {
    const float* x = (const float*)d_in[0];
    const int* ei = (const int*)d_in[1];
    const int* batch = (const int*)d_in[2];
    // d_in[3] = n_graphs (device scalar); G == out_size since output is [G,1]
    const float* W1 = (const float*)d_in[4];
    const float* b1 = (const float*)d_in[5];
    const float* W2 = (const float*)d_in[6];
    const float* b2 = (const float*)d_in[7];
    const float* W3 = (const float*)d_in[8];
    const float* b3 = (const float*)d_in[9];
    const float* Wf1 = (const float*)d_in[10];
    const float* bf1 = (const float*)d_in[11];
    const float* Wf2 = (const float*)d_in[12];
    const float* bf2 = (const float*)d_in[13];
    const float* Wf3 = (const float*)d_in[14];
    const float* bf3 = (const float*)d_in[15];

    const int N = in_sizes[0] / 128;
    const int E = in_sizes[1] / 2;
    const int G = out_size;

    const int* src = ei;
    const int* dst = ei + E;

    // workspace carve (256B aligned)
    char* w = (char*)d_ws;
    size_t off = 0;
    auto alloc = [&](size_t bytes) -> void* {
        void* p = w + off;
        off += (bytes + 255) / 256 * 256;
        return p;
    };
    float* U = (float*)alloc((size_t)N * 128 * 4);
    float* H = (float*)alloc((size_t)N * 128 * 4);
    int* csr_src = (int*)alloc((size_t)E * 4);
    int* rowstart = (int*)alloc((size_t)(N + 1) * 4);
    int* cnt = (int*)alloc((size_t)N * 4);
    int* cursor = (int*)alloc((size_t)N * 4);
    float* dinv = (float*)alloc((size_t)N * 4);
    int* part = (int*)alloc(1024 * 4);
    int* boff = (int*)alloc(1024 * 4);
    int* gstart = (int*)alloc((size_t)(G + 1) * 4);
    float* gfeat = (float*)alloc((size_t)G * 256 * 4);
    float* out = (float*)d_out;

    const int nblk = (N + 1023) / 1024;

    hipMemsetAsync(cnt, 0, (size_t)N * 4, stream);
    hipMemsetAsync(cursor, 0, (size_t)N * 4, stream);

    k_count<<<dim3((E + 255) / 256), dim3(256), 0, stream>>>(dst, E, cnt);
    k_scan1<<<dim3(nblk), dim3(256), 0, stream>>>(cnt, N, part);
    k_scan2<<<dim3(1), dim3(1024), 0, stream>>>(part, boff, nblk, rowstart, N, E);
    k_scan3<<<dim3(nblk), dim3(256), 0, stream>>>(cnt, N, boff, rowstart);
    k_dinv<<<dim3((N + 255) / 256), dim3(256), 0, stream>>>(cnt, dinv, N);
    k_fill<<<dim3((E + 255) / 256), dim3(256), 0, stream>>>(src, dst, E, rowstart, cursor,
                                                            csr_src);

    const int gemmGrid = (N + 127) / 128;
    const int aggGrid = (N + 3) / 4;

    // conv1: H = relu(agg(x @ W1) + b1)
    k_gemm<<<dim3(gemmGrid), dim3(256), 0, stream>>>(x, W1, dinv, U, N);
    k_agg<0><<<dim3(aggGrid), dim3(256), 0, stream>>>(U, rowstart, csr_src, dinv, b1, H, N);

    // conv2: H = relu(agg(H @ W2) + b2) + H
    k_gemm<<<dim3(gemmGrid), dim3(256), 0, stream>>>(H, W2, dinv, U, N);
    k_agg<1><<<dim3(aggGrid), dim3(256), 0, stream>>>(U, rowstart, csr_src, dinv, b2, H, N);

    // conv3: H = relu(agg(H @ W3) + b3) + H
    k_gemm<<<dim3(gemmGrid), dim3(256), 0, stream>>>(H, W3, dinv, U, N);
    k_agg<1><<<dim3(aggGrid), dim3(256), 0, stream>>>(U, rowstart, csr_src, dinv, b3, H, N);

    // pooling + head
    k_gstart<<<dim3((G + 256) / 256), dim3(256), 0, stream>>>(batch, N, G, gstart);
    k_pool<<<dim3(G), dim3(256), 0, stream>>>(H, gstart, gfeat);
    k_mlp<<<dim3(G), dim3(128), 0, stream>>>(gfeat, Wf1, bf1, Wf2, bf2, Wf3, bf3, out);
}

// Round 3
// 890.046 us; speedup vs baseline: 1.1824x; 1.0170x over previous
//
#include <hip/hip_runtime.h>
#include <hip/hip_bf16.h>

// ---------------- preprocessing ----------------

__global__ __launch_bounds__(256) void k_count(const int* __restrict__ dst, int E,
                                               int* __restrict__ cnt) {
    int e = blockIdx.x * 256 + threadIdx.x;
    if (e < E) atomicAdd(&cnt[dst[e]], 1);
}

// chunk = 1024 elements per block, thread t owns elements [t*4, t*4+4)
__global__ __launch_bounds__(256) void k_scan1(const int* __restrict__ cnt, int N,
                                               int* __restrict__ part) {
    __shared__ int sh[256];
    int base = blockIdx.x * 1024;
    int t = threadIdx.x;
    int s = 0;
#pragma unroll
    for (int i = 0; i < 4; i++) {
        int idx = base + t * 4 + i;
        if (idx < N) s += cnt[idx];
    }
    sh[t] = s;
    __syncthreads();
    for (int off = 128; off > 0; off >>= 1) {
        if (t < off) sh[t] += sh[t + off];
        __syncthreads();
    }
    if (t == 0) part[blockIdx.x] = sh[0];
}

__global__ __launch_bounds__(1024) void k_scan2(const int* __restrict__ part,
                                                int* __restrict__ boff, int nblk,
                                                int* __restrict__ rowstart, int N, int E) {
    __shared__ int sh[1024];
    int t = threadIdx.x;
    int v = (t < nblk) ? part[t] : 0;
    sh[t] = v;
    __syncthreads();
    for (int off = 1; off < 1024; off <<= 1) {
        int x = (t >= off) ? sh[t - off] : 0;
        __syncthreads();
        sh[t] += x;
        __syncthreads();
    }
    if (t < nblk) boff[t] = sh[t] - v;  // exclusive
    if (t == 0) rowstart[N] = E;
}

__global__ __launch_bounds__(256) void k_scan3(const int* __restrict__ cnt, int N,
                                               const int* __restrict__ boff,
                                               int* __restrict__ rowstart) {
    __shared__ int sh[256];
    int base = blockIdx.x * 1024;
    int t = threadIdx.x;
    int idx = base + t * 4;
    int v0 = 0, v1 = 0, v2 = 0, v3 = 0;
    if (idx + 3 < N) {
        int4 q = *(const int4*)&cnt[idx];
        v0 = q.x; v1 = q.y; v2 = q.z; v3 = q.w;
    } else {
        if (idx < N) v0 = cnt[idx];
        if (idx + 1 < N) v1 = cnt[idx + 1];
        if (idx + 2 < N) v2 = cnt[idx + 2];
        if (idx + 3 < N) v3 = cnt[idx + 3];
    }
    int tot = v0 + v1 + v2 + v3;
    sh[t] = tot;
    __syncthreads();
    for (int off = 1; off < 256; off <<= 1) {
        int x = (t >= off) ? sh[t - off] : 0;
        __syncthreads();
        sh[t] += x;
        __syncthreads();
    }
    int excl = sh[t] - tot;
    int b0 = boff[blockIdx.x] + excl;
    if (idx + 3 < N) {
        int4 w = make_int4(b0, b0 + v0, b0 + v0 + v1, b0 + v0 + v1 + v2);
        *(int4*)&rowstart[idx] = w;
    } else {
        if (idx < N) rowstart[idx] = b0;
        if (idx + 1 < N) rowstart[idx + 1] = b0 + v0;
        if (idx + 2 < N) rowstart[idx + 2] = b0 + v0 + v1;
        if (idx + 3 < N) rowstart[idx + 3] = b0 + v0 + v1 + v2;
    }
}

__global__ __launch_bounds__(256) void k_dinv(const int* __restrict__ cnt,
                                              float* __restrict__ dinv, int N) {
    int n = blockIdx.x * 256 + threadIdx.x;
    if (n < N) dinv[n] = rsqrtf((float)cnt[n] + 1.0f);  // deg = in-edges + self-loop
}

__global__ __launch_bounds__(256) void k_fill(const int* __restrict__ src,
                                              const int* __restrict__ dst, int E,
                                              const int* __restrict__ rowstart,
                                              int* __restrict__ cursor,
                                              int* __restrict__ csr_src) {
    int e = blockIdx.x * 256 + threadIdx.x;
    if (e >= E) return;
    int s = src[e], d = dst[e];
    int pos = rowstart[d] + atomicAdd(&cursor[d], 1);
    csr_src[pos] = s;
}

// ---------------- GEMM: U = dinv .* (A @ W)  (A:[N,128] f32, W:[128,128]) -------
// 128-row x 128-col tile per block, 256 threads, 8x8 per thread, K in chunks of 32.
// Epilogue scales row r by dinv[r] so the aggregation needs no per-edge weight:
//   sum_e dinv_s*dinv_d*T_s = dinv_d * sum_e U_s,  U = dinv .* T.

__global__ __launch_bounds__(256) void k_gemm(const float* __restrict__ A,
                                              const float* __restrict__ W,
                                              const float* __restrict__ dinv,
                                              float* __restrict__ U, int N) {
    __shared__ float AshT[32][132];  // [k][row], pad 132 for transpose-store
    __shared__ float Wsh[32][132];   // [k][col]
    int t = threadIdx.x;
    int tr = t >> 4;        // 0..15
    int tc = t & 15;        // 0..15
    int rowBase = blockIdx.x * 128;
    float acc[8][8] = {};

    for (int kc = 0; kc < 4; kc++) {
#pragma unroll
        for (int i = 0; i < 4; i++) {
            int q = t + i * 256;     // float4 id, 0..1023
            int row = q >> 3;        // 0..127
            int c4 = q & 7;          // 0..7
            int gr = rowBase + row;
            float4 a4 = make_float4(0.f, 0.f, 0.f, 0.f);
            if (gr < N) a4 = *(const float4*)&A[(size_t)gr * 128 + kc * 32 + c4 * 4];
            AshT[c4 * 4 + 0][row] = a4.x;
            AshT[c4 * 4 + 1][row] = a4.y;
            AshT[c4 * 4 + 2][row] = a4.z;
            AshT[c4 * 4 + 3][row] = a4.w;
        }
#pragma unroll
        for (int i = 0; i < 4; i++) {
            int q = t + i * 256;     // 0..1023
            int k = q >> 5;          // 0..31
            int c4 = q & 31;         // 0..31
            float4 w4 = *(const float4*)&W[(size_t)(kc * 32 + k) * 128 + c4 * 4];
            *(float4*)&Wsh[k][c4 * 4] = w4;
        }
        __syncthreads();
#pragma unroll
        for (int k = 0; k < 32; k++) {
            float4 a0 = *(const float4*)&AshT[k][tr * 8];
            float4 a1 = *(const float4*)&AshT[k][tr * 8 + 4];
            float4 w0 = *(const float4*)&Wsh[k][tc * 8];
            float4 w1 = *(const float4*)&Wsh[k][tc * 8 + 4];
            float a[8] = {a0.x, a0.y, a0.z, a0.w, a1.x, a1.y, a1.z, a1.w};
            float w[8] = {w0.x, w0.y, w0.z, w0.w, w1.x, w1.y, w1.z, w1.w};
#pragma unroll
            for (int i = 0; i < 8; i++)
#pragma unroll
                for (int j = 0; j < 8; j++) acc[i][j] = fmaf(a[i], w[j], acc[i][j]);
        }
        __syncthreads();
    }
#pragma unroll
    for (int i = 0; i < 8; i++) {
        int gr = rowBase + tr * 8 + i;
        if (gr < N) {
            float dv = dinv[gr];
            *(float4*)&U[(size_t)gr * 128 + tc * 8] =
                make_float4(dv * acc[i][0], dv * acc[i][1], dv * acc[i][2], dv * acc[i][3]);
            *(float4*)&U[(size_t)gr * 128 + tc * 8 + 4] =
                make_float4(dv * acc[i][4], dv * acc[i][5], dv * acc[i][6], dv * acc[i][7]);
        }
    }
}

// ---------------- aggregation ----------------
// H[n] = relu(dinv[n] * (U[n] + sum_{e in CSR(n)} U[src_e]) + bias) (+ H[n] if RES)
// One wave per node; two 32-lane groups own contiguous halves of the edge list.
// 4 independent 512B row gathers in flight per group (4KB/wave), indices
// software-pipelined one iteration ahead so the index load is off the chain.

template <int RES>
__global__ __launch_bounds__(256) void k_agg(const float* __restrict__ U,
                                             const int* __restrict__ rowstart,
                                             const int* __restrict__ csr_src,
                                             const float* __restrict__ dinv,
                                             const float* __restrict__ bias,
                                             float* __restrict__ H, int N) {
    int wave = threadIdx.x >> 6;  // 0..3
    int lane = threadIdx.x & 63;
    int n = blockIdx.x * 4 + wave;
    if (n >= N) return;
    int g = lane >> 5;   // edge group 0/1
    int l = lane & 31;   // channel quad: channels l*4 .. l*4+3
    int e0 = rowstart[n], e1 = rowstart[n + 1];
    int half = (e1 - e0) >> 1;
    int a0 = g ? (e0 + half) : e0;
    int a1 = g ? e1 : (e0 + half);

    float4 A0 = {0.f, 0.f, 0.f, 0.f};
    float4 A1 = {0.f, 0.f, 0.f, 0.f};
    float4 A2 = {0.f, 0.f, 0.f, 0.f};
    float4 A3 = {0.f, 0.f, 0.f, 0.f};

    int e = a0;
    if (e + 4 <= a1) {
        int s0 = csr_src[e], s1 = csr_src[e + 1], s2 = csr_src[e + 2], s3 = csr_src[e + 3];
        for (; e + 8 <= a1; e += 4) {
            int t0 = csr_src[e + 4], t1 = csr_src[e + 5];
            int t2 = csr_src[e + 6], t3 = csr_src[e + 7];
            float4 r0 = *(const float4*)&U[(size_t)s0 * 128 + l * 4];
            float4 r1 = *(const float4*)&U[(size_t)s1 * 128 + l * 4];
            float4 r2 = *(const float4*)&U[(size_t)s2 * 128 + l * 4];
            float4 r3 = *(const float4*)&U[(size_t)s3 * 128 + l * 4];
            A0.x += r0.x; A0.y += r0.y; A0.z += r0.z; A0.w += r0.w;
            A1.x += r1.x; A1.y += r1.y; A1.z += r1.z; A1.w += r1.w;
            A2.x += r2.x; A2.y += r2.y; A2.z += r2.z; A2.w += r2.w;
            A3.x += r3.x; A3.y += r3.y; A3.z += r3.z; A3.w += r3.w;
            s0 = t0; s1 = t1; s2 = t2; s3 = t3;
        }
        {
            float4 r0 = *(const float4*)&U[(size_t)s0 * 128 + l * 4];
            float4 r1 = *(const float4*)&U[(size_t)s1 * 128 + l * 4];
            float4 r2 = *(const float4*)&U[(size_t)s2 * 128 + l * 4];
            float4 r3 = *(const float4*)&U[(size_t)s3 * 128 + l * 4];
            A0.x += r0.x; A0.y += r0.y; A0.z += r0.z; A0.w += r0.w;
            A1.x += r1.x; A1.y += r1.y; A1.z += r1.z; A1.w += r1.w;
            A2.x += r2.x; A2.y += r2.y; A2.z += r2.z; A2.w += r2.w;
            A3.x += r3.x; A3.y += r3.y; A3.z += r3.z; A3.w += r3.w;
            e += 4;
        }
    }
    for (; e < a1; e++) {
        int s = csr_src[e];
        float4 r = *(const float4*)&U[(size_t)s * 128 + l * 4];
        A0.x += r.x; A0.y += r.y; A0.z += r.z; A0.w += r.w;
    }

    float ax = (A0.x + A1.x) + (A2.x + A3.x);
    float ay = (A0.y + A1.y) + (A2.y + A3.y);
    float az = (A0.z + A1.z) + (A2.z + A3.z);
    float aw = (A0.w + A1.w) + (A2.w + A3.w);

    // combine the two groups (xor 32 sums both halves into every lane)
    ax += __shfl_xor(ax, 32);
    ay += __shfl_xor(ay, 32);
    az += __shfl_xor(az, 32);
    aw += __shfl_xor(aw, 32);

    if (g == 0) {
        float4 self = *(const float4*)&U[(size_t)n * 128 + l * 4];
        float4 bi = *(const float4*)&bias[l * 4];
        float dn = dinv[n];
        float4 out;
        out.x = fmaxf(dn * (ax + self.x) + bi.x, 0.f);
        out.y = fmaxf(dn * (ay + self.y) + bi.y, 0.f);
        out.z = fmaxf(dn * (az + self.z) + bi.z, 0.f);
        out.w = fmaxf(dn * (aw + self.w) + bi.w, 0.f);
        if (RES) {
            float4 h = *(const float4*)&H[(size_t)n * 128 + l * 4];
            out.x += h.x; out.y += h.y; out.z += h.z; out.w += h.w;
        }
        *(float4*)&H[(size_t)n * 128 + l * 4] = out;
    }
}

// ---------------- pooling ----------------

__global__ __launch_bounds__(256) void k_gstart(const int* __restrict__ batch, int N, int G,
                                                int* __restrict__ gstart) {
    int g = blockIdx.x * 256 + threadIdx.x;
    if (g > G) return;
    if (g == G) { gstart[g] = N; return; }
    int lo = 0, hi = N;
    while (lo < hi) {
        int mid = (lo + hi) >> 1;
        if (batch[mid] < g) lo = mid + 1; else hi = mid;
    }
    gstart[g] = lo;
}

// one block (256 threads) per graph; two halves of the node range in parallel
__global__ __launch_bounds__(256) void k_pool(const float* __restrict__ H,
                                              const int* __restrict__ gstart,
                                              float* __restrict__ gfeat) {
    __shared__ float ssum[256];
    __shared__ float smax[256];
    int g = blockIdx.x;
    int c = threadIdx.x & 127;
    int half = threadIdx.x >> 7;
    int i0 = gstart[g], i1 = gstart[g + 1];
    int cn = i1 - i0;
    int mid = i0 + (cn >> 1);
    int a0 = half ? mid : i0;
    int a1 = half ? i1 : mid;
    float s = 0.f, m = -3.4e38f;
    for (int i = a0; i < a1; i++) {
        float v = H[(size_t)i * 128 + c];
        s += v;
        m = fmaxf(m, v);
    }
    ssum[threadIdx.x] = s;
    smax[threadIdx.x] = m;
    __syncthreads();
    if (half == 0) {
        float st = ssum[c] + ssum[c + 128];
        float mt = fmaxf(smax[c], smax[c + 128]);
        float mean = (cn > 0) ? st / (float)cn : 0.f;
        if (cn == 0) mt = 0.f;
        gfeat[g * 256 + c] = mean;
        gfeat[g * 256 + 128 + c] = mt;
    }
}

// ---------------- MLP head ----------------

__global__ __launch_bounds__(128) void k_mlp(const float* __restrict__ gfeat,
                                             const float* __restrict__ Wf1,
                                             const float* __restrict__ bf1,
                                             const float* __restrict__ Wf2,
                                             const float* __restrict__ bf2,
                                             const float* __restrict__ Wf3,
                                             const float* __restrict__ bf3,
                                             float* __restrict__ out) {
    __shared__ float grow[256];
    __shared__ float o1[128];
    __shared__ float o2[64];
    int g = blockIdx.x;
    int t = threadIdx.x;
    grow[t] = gfeat[g * 256 + t];
    grow[t + 128] = gfeat[g * 256 + 128 + t];
    __syncthreads();
    float acc = bf1[t];
#pragma unroll 8
    for (int k = 0; k < 256; k++) acc = fmaf(grow[k], Wf1[k * 128 + t], acc);
    o1[t] = fmaxf(acc, 0.f);
    __syncthreads();
    if (t < 64) {
        float a2 = bf2[t];
#pragma unroll 8
        for (int k = 0; k < 128; k++) a2 = fmaf(o1[k], Wf2[k * 64 + t], a2);
        o2[t] = fmaxf(a2, 0.f);
    }
    __syncthreads();
    if (t < 64) {
        float p = o2[t] * Wf3[t];
        for (int off = 32; off > 0; off >>= 1) p += __shfl_down(p, off);
        if (t == 0) out[g] = p + bf3[0];
    }
}

// ---------------- launch ----------------

extern "C" void kernel_launch(void* const* d_in, const int* in_sizes, int n_in,
                              void* d_out, int out_size, void* d_ws, size_t ws_size,
                              hipStream_t stream) {
    const float* x = (const float*)d_in[0];
    const int* ei = (const int*)d_in[1];
    const int* batch = (const int*)d_in[2];
    // d_in[3] = n_graphs (device scalar); G == out_size since output is [G,1]
    const float* W1 = (const float*)d_in[4];
    const float* b1 = (const float*)d_in[5];
    const float* W2 = (const float*)d_in[6];
    const float* b2 = (const float*)d_in[7];
    const float* W3 = (const float*)d_in[8];
    const float* b3 = (const float*)d_in[9];
    const float* Wf1 = (const float*)d_in[10];
    const float* bf1 = (const float*)d_in[11];
    const float* Wf2 = (const float*)d_in[12];
    const float* bf2 = (const float*)d_in[13];
    const float* Wf3 = (const float*)d_in[14];
    const float* bf3 = (const float*)d_in[15];

    const int N = in_sizes[0] / 128;
    const int E = in_sizes[1] / 2;
    const int G = out_size;

    const int* src = ei;
    const int* dst = ei + E;

    // workspace carve (256B aligned)
    char* w = (char*)d_ws;
    size_t off = 0;
    auto alloc = [&](size_t bytes) -> void* {
        void* p = w + off;
        off += (bytes + 255) / 256 * 256;
        return p;
    };
    float* U = (float*)alloc((size_t)N * 128 * 4);
    float* H = (float*)alloc((size_t)N * 128 * 4);
    int* csr_src = (int*)alloc((size_t)E * 4);
    int* rowstart = (int*)alloc((size_t)(N + 1) * 4);
    int* cnt = (int*)alloc((size_t)N * 4);
    int* cursor = (int*)alloc((size_t)N * 4);
    float* dinv = (float*)alloc((size_t)N * 4);
    int* part = (int*)alloc(1024 * 4);
    int* boff = (int*)alloc(1024 * 4);
    int* gstart = (int*)alloc((size_t)(G + 1) * 4);
    float* gfeat = (float*)alloc((size_t)G * 256 * 4);
    float* out = (float*)d_out;

    const int nblk = (N + 1023) / 1024;

    hipMemsetAsync(cnt, 0, (size_t)N * 4, stream);
    hipMemsetAsync(cursor, 0, (size_t)N * 4, stream);

    k_count<<<dim3((E + 255) / 256), dim3(256), 0, stream>>>(dst, E, cnt);
    k_scan1<<<dim3(nblk), dim3(256), 0, stream>>>(cnt, N, part);
    k_scan2<<<dim3(1), dim3(1024), 0, stream>>>(part, boff, nblk, rowstart, N, E);
    k_scan3<<<dim3(nblk), dim3(256), 0, stream>>>(cnt, N, boff, rowstart);
    k_dinv<<<dim3((N + 255) / 256), dim3(256), 0, stream>>>(cnt, dinv, N);
    k_fill<<<dim3((E + 255) / 256), dim3(256), 0, stream>>>(src, dst, E, rowstart, cursor,
                                                            csr_src);

    const int gemmGrid = (N + 127) / 128;
    const int aggGrid = (N + 3) / 4;

    // conv1: H = relu(agg(x @ W1) + b1)
    k_gemm<<<dim3(gemmGrid), dim3(256), 0, stream>>>(x, W1, dinv, U, N);
    k_agg<0><<<dim3(aggGrid), dim3(256), 0, stream>>>(U, rowstart, csr_src, dinv, b1, H, N);

    // conv2: H = relu(agg(H @ W2) + b2) + H
    k_gemm<<<dim3(gemmGrid), dim3(256), 0, stream>>>(H, W2, dinv, U, N);
    k_agg<1><<<dim3(aggGrid), dim3(256), 0, stream>>>(U, rowstart, csr_src, dinv, b2, H, N);

    // conv3: H = relu(agg(H @ W3) + b3) + H
    k_gemm<<<dim3(gemmGrid), dim3(256), 0, stream>>>(H, W3, dinv, U, N);
    k_agg<1><<<dim3(aggGrid), dim3(256), 0, stream>>>(U, rowstart, csr_src, dinv, b3, H, N);

    // pooling + head
    k_gstart<<<dim3((G + 256) / 256), dim3(256), 0, stream>>>(batch, N, G, gstart);
    k_pool<<<dim3(G), dim3(256), 0, stream>>>(H, gstart, gfeat);
    k_mlp<<<dim3(G), dim3(128), 0, stream>>>(gfeat, Wf1, bf1, Wf2, bf2, Wf3, bf3, out);
}

// Round 4
// 748.513 us; speedup vs baseline: 1.4060x; 1.1891x over previous
//
#include <hip/hip_runtime.h>
#include <hip/hip_bf16.h>

// ---------------- preprocessing ----------------

__global__ __launch_bounds__(256) void k_count(const int* __restrict__ dst, int E,
                                               int* __restrict__ cnt) {
    int e = blockIdx.x * 256 + threadIdx.x;
    if (e < E) atomicAdd(&cnt[dst[e]], 1);
}

// chunk = 1024 elements per block, thread t owns elements [t*4, t*4+4)
__global__ __launch_bounds__(256) void k_scan1(const int* __restrict__ cnt, int N,
                                               int* __restrict__ part) {
    __shared__ int sh[256];
    int base = blockIdx.x * 1024;
    int t = threadIdx.x;
    int s = 0;
#pragma unroll
    for (int i = 0; i < 4; i++) {
        int idx = base + t * 4 + i;
        if (idx < N) s += cnt[idx];
    }
    sh[t] = s;
    __syncthreads();
    for (int off = 128; off > 0; off >>= 1) {
        if (t < off) sh[t] += sh[t + off];
        __syncthreads();
    }
    if (t == 0) part[blockIdx.x] = sh[0];
}

__global__ __launch_bounds__(1024) void k_scan2(const int* __restrict__ part,
                                                int* __restrict__ boff, int nblk,
                                                int* __restrict__ rowstart, int N, int E) {
    __shared__ int sh[1024];
    int t = threadIdx.x;
    int v = (t < nblk) ? part[t] : 0;
    sh[t] = v;
    __syncthreads();
    for (int off = 1; off < 1024; off <<= 1) {
        int x = (t >= off) ? sh[t - off] : 0;
        __syncthreads();
        sh[t] += x;
        __syncthreads();
    }
    if (t < nblk) boff[t] = sh[t] - v;  // exclusive
    if (t == 0) rowstart[N] = E;
}

__global__ __launch_bounds__(256) void k_scan3(const int* __restrict__ cnt, int N,
                                               const int* __restrict__ boff,
                                               int* __restrict__ rowstart) {
    __shared__ int sh[256];
    int base = blockIdx.x * 1024;
    int t = threadIdx.x;
    int idx = base + t * 4;
    int v0 = 0, v1 = 0, v2 = 0, v3 = 0;
    if (idx + 3 < N) {
        int4 q = *(const int4*)&cnt[idx];
        v0 = q.x; v1 = q.y; v2 = q.z; v3 = q.w;
    } else {
        if (idx < N) v0 = cnt[idx];
        if (idx + 1 < N) v1 = cnt[idx + 1];
        if (idx + 2 < N) v2 = cnt[idx + 2];
        if (idx + 3 < N) v3 = cnt[idx + 3];
    }
    int tot = v0 + v1 + v2 + v3;
    sh[t] = tot;
    __syncthreads();
    for (int off = 1; off < 256; off <<= 1) {
        int x = (t >= off) ? sh[t - off] : 0;
        __syncthreads();
        sh[t] += x;
        __syncthreads();
    }
    int excl = sh[t] - tot;
    int b0 = boff[blockIdx.x] + excl;
    if (idx + 3 < N) {
        int4 w = make_int4(b0, b0 + v0, b0 + v0 + v1, b0 + v0 + v1 + v2);
        *(int4*)&rowstart[idx] = w;
    } else {
        if (idx < N) rowstart[idx] = b0;
        if (idx + 1 < N) rowstart[idx + 1] = b0 + v0;
        if (idx + 2 < N) rowstart[idx + 2] = b0 + v0 + v1;
        if (idx + 3 < N) rowstart[idx + 3] = b0 + v0 + v1 + v2;
    }
}

__global__ __launch_bounds__(256) void k_dinv(const int* __restrict__ cnt,
                                              float* __restrict__ dinv, int N) {
    int n = blockIdx.x * 256 + threadIdx.x;
    if (n < N) dinv[n] = rsqrtf((float)cnt[n] + 1.0f);  // deg = in-edges + self-loop
}

__global__ __launch_bounds__(256) void k_fill(const int* __restrict__ src,
                                              const int* __restrict__ dst, int E,
                                              const int* __restrict__ rowstart,
                                              int* __restrict__ cursor,
                                              int* __restrict__ csr_src) {
    int e = blockIdx.x * 256 + threadIdx.x;
    if (e >= E) return;
    int s = src[e], d = dst[e];
    int pos = rowstart[d] + atomicAdd(&cursor[d], 1);
    csr_src[pos] = s;
}

// ---- bf16 pack/unpack helpers (RNE) ----
__device__ inline unsigned pack_bf16_pair(float lo, float hi) {
    unsigned ul = __float_as_uint(lo);
    unsigned uh = __float_as_uint(hi);
    ul = (ul + 0x7FFFu + ((ul >> 16) & 1u)) >> 16;
    uh = (uh + 0x7FFFu + ((uh >> 16) & 1u)) & 0xFFFF0000u;
    return ul | uh;
}

__device__ inline float4 unpack_bf16_quad(uint2 q) {
    float4 r;
    r.x = __uint_as_float(q.x << 16);
    r.y = __uint_as_float(q.x & 0xFFFF0000u);
    r.z = __uint_as_float(q.y << 16);
    r.w = __uint_as_float(q.y & 0xFFFF0000u);
    return r;
}

// ---------------- GEMM: U = bf16(dinv .* (A @ W))  (A:[N,128] f32, W:[128,128]) ----
// 128x128 tile per block, 256 threads, 8x8 per thread, fp32 accumulate.
// Epilogue scales row r by dinv[r] and stores bf16 (one RNE rounding per element):
//   sum_e dinv_s*dinv_d*T_s = dinv_d * sum_e U_s,  U = dinv .* T.

__global__ __launch_bounds__(256) void k_gemm(const float* __restrict__ A,
                                              const float* __restrict__ W,
                                              const float* __restrict__ dinv,
                                              unsigned short* __restrict__ U, int N) {
    __shared__ float AshT[32][132];  // [k][row], pad 132 for transpose-store
    __shared__ float Wsh[32][132];   // [k][col]
    int t = threadIdx.x;
    int tr = t >> 4;        // 0..15
    int tc = t & 15;        // 0..15
    int rowBase = blockIdx.x * 128;
    float acc[8][8] = {};

    for (int kc = 0; kc < 4; kc++) {
#pragma unroll
        for (int i = 0; i < 4; i++) {
            int q = t + i * 256;     // float4 id, 0..1023
            int row = q >> 3;        // 0..127
            int c4 = q & 7;          // 0..7
            int gr = rowBase + row;
            float4 a4 = make_float4(0.f, 0.f, 0.f, 0.f);
            if (gr < N) a4 = *(const float4*)&A[(size_t)gr * 128 + kc * 32 + c4 * 4];
            AshT[c4 * 4 + 0][row] = a4.x;
            AshT[c4 * 4 + 1][row] = a4.y;
            AshT[c4 * 4 + 2][row] = a4.z;
            AshT[c4 * 4 + 3][row] = a4.w;
        }
#pragma unroll
        for (int i = 0; i < 4; i++) {
            int q = t + i * 256;     // 0..1023
            int k = q >> 5;          // 0..31
            int c4 = q & 31;         // 0..31
            float4 w4 = *(const float4*)&W[(size_t)(kc * 32 + k) * 128 + c4 * 4];
            *(float4*)&Wsh[k][c4 * 4] = w4;
        }
        __syncthreads();
#pragma unroll
        for (int k = 0; k < 32; k++) {
            float4 a0 = *(const float4*)&AshT[k][tr * 8];
            float4 a1 = *(const float4*)&AshT[k][tr * 8 + 4];
            float4 w0 = *(const float4*)&Wsh[k][tc * 8];
            float4 w1 = *(const float4*)&Wsh[k][tc * 8 + 4];
            float a[8] = {a0.x, a0.y, a0.z, a0.w, a1.x, a1.y, a1.z, a1.w};
            float w[8] = {w0.x, w0.y, w0.z, w0.w, w1.x, w1.y, w1.z, w1.w};
#pragma unroll
            for (int i = 0; i < 8; i++)
#pragma unroll
                for (int j = 0; j < 8; j++) acc[i][j] = fmaf(a[i], w[j], acc[i][j]);
        }
        __syncthreads();
    }
#pragma unroll
    for (int i = 0; i < 8; i++) {
        int gr = rowBase + tr * 8 + i;
        if (gr < N) {
            float dv = dinv[gr];
            uint4 p;
            p.x = pack_bf16_pair(dv * acc[i][0], dv * acc[i][1]);
            p.y = pack_bf16_pair(dv * acc[i][2], dv * acc[i][3]);
            p.z = pack_bf16_pair(dv * acc[i][4], dv * acc[i][5]);
            p.w = pack_bf16_pair(dv * acc[i][6], dv * acc[i][7]);
            *(uint4*)&U[(size_t)gr * 128 + tc * 8] = p;
        }
    }
}

// ---------------- aggregation ----------------
// H[n] = relu(dinv[n] * (U[n] + sum_{e in CSR(n)} U[src_e]) + bias) (+ H[n] if RES)
// One wave per node; two 32-lane groups own contiguous halves of the edge list.
// U rows are bf16 (256B): lane l loads 8B (channels l*4..l*4+3), fp32 accumulate.

template <int RES>
__global__ __launch_bounds__(256) void k_agg(const unsigned short* __restrict__ U,
                                             const int* __restrict__ rowstart,
                                             const int* __restrict__ csr_src,
                                             const float* __restrict__ dinv,
                                             const float* __restrict__ bias,
                                             float* __restrict__ H, int N) {
    int wave = threadIdx.x >> 6;  // 0..3
    int lane = threadIdx.x & 63;
    int n = blockIdx.x * 4 + wave;
    if (n >= N) return;
    int g = lane >> 5;   // edge group 0/1
    int l = lane & 31;   // channel quad: channels l*4 .. l*4+3
    int e0 = rowstart[n], e1 = rowstart[n + 1];
    int half = (e1 - e0) >> 1;
    int a0 = g ? (e0 + half) : e0;
    int a1 = g ? e1 : (e0 + half);

    float4 A0 = {0.f, 0.f, 0.f, 0.f};
    float4 A1 = {0.f, 0.f, 0.f, 0.f};
    float4 A2 = {0.f, 0.f, 0.f, 0.f};
    float4 A3 = {0.f, 0.f, 0.f, 0.f};

    int e = a0;
    for (; e + 4 <= a1; e += 4) {
        int s0 = csr_src[e], s1 = csr_src[e + 1];
        int s2 = csr_src[e + 2], s3 = csr_src[e + 3];
        uint2 q0 = *(const uint2*)&U[(size_t)s0 * 128 + l * 4];
        uint2 q1 = *(const uint2*)&U[(size_t)s1 * 128 + l * 4];
        uint2 q2 = *(const uint2*)&U[(size_t)s2 * 128 + l * 4];
        uint2 q3 = *(const uint2*)&U[(size_t)s3 * 128 + l * 4];
        float4 r0 = unpack_bf16_quad(q0);
        float4 r1 = unpack_bf16_quad(q1);
        float4 r2 = unpack_bf16_quad(q2);
        float4 r3 = unpack_bf16_quad(q3);
        A0.x += r0.x; A0.y += r0.y; A0.z += r0.z; A0.w += r0.w;
        A1.x += r1.x; A1.y += r1.y; A1.z += r1.z; A1.w += r1.w;
        A2.x += r2.x; A2.y += r2.y; A2.z += r2.z; A2.w += r2.w;
        A3.x += r3.x; A3.y += r3.y; A3.z += r3.z; A3.w += r3.w;
    }
    for (; e < a1; e++) {
        int s = csr_src[e];
        uint2 q = *(const uint2*)&U[(size_t)s * 128 + l * 4];
        float4 r = unpack_bf16_quad(q);
        A0.x += r.x; A0.y += r.y; A0.z += r.z; A0.w += r.w;
    }

    float ax = (A0.x + A1.x) + (A2.x + A3.x);
    float ay = (A0.y + A1.y) + (A2.y + A3.y);
    float az = (A0.z + A1.z) + (A2.z + A3.z);
    float aw = (A0.w + A1.w) + (A2.w + A3.w);

    // combine the two groups (xor 32 sums both halves into every lane)
    ax += __shfl_xor(ax, 32);
    ay += __shfl_xor(ay, 32);
    az += __shfl_xor(az, 32);
    aw += __shfl_xor(aw, 32);

    if (g == 0) {
        uint2 qs = *(const uint2*)&U[(size_t)n * 128 + l * 4];
        float4 self = unpack_bf16_quad(qs);
        float4 bi = *(const float4*)&bias[l * 4];
        float dn = dinv[n];
        float4 out;
        out.x = fmaxf(dn * (ax + self.x) + bi.x, 0.f);
        out.y = fmaxf(dn * (ay + self.y) + bi.y, 0.f);
        out.z = fmaxf(dn * (az + self.z) + bi.z, 0.f);
        out.w = fmaxf(dn * (aw + self.w) + bi.w, 0.f);
        if (RES) {
            float4 h = *(const float4*)&H[(size_t)n * 128 + l * 4];
            out.x += h.x; out.y += h.y; out.z += h.z; out.w += h.w;
        }
        *(float4*)&H[(size_t)n * 128 + l * 4] = out;
    }
}

// ---------------- pooling ----------------

__global__ __launch_bounds__(256) void k_gstart(const int* __restrict__ batch, int N, int G,
                                                int* __restrict__ gstart) {
    int g = blockIdx.x * 256 + threadIdx.x;
    if (g > G) return;
    if (g == G) { gstart[g] = N; return; }
    int lo = 0, hi = N;
    while (lo < hi) {
        int mid = (lo + hi) >> 1;
        if (batch[mid] < g) lo = mid + 1; else hi = mid;
    }
    gstart[g] = lo;
}

// one block (256 threads) per graph; two halves of the node range in parallel
__global__ __launch_bounds__(256) void k_pool(const float* __restrict__ H,
                                              const int* __restrict__ gstart,
                                              float* __restrict__ gfeat) {
    __shared__ float ssum[256];
    __shared__ float smax[256];
    int g = blockIdx.x;
    int c = threadIdx.x & 127;
    int half = threadIdx.x >> 7;
    int i0 = gstart[g], i1 = gstart[g + 1];
    int cn = i1 - i0;
    int mid = i0 + (cn >> 1);
    int a0 = half ? mid : i0;
    int a1 = half ? i1 : mid;
    float s = 0.f, m = -3.4e38f;
    for (int i = a0; i < a1; i++) {
        float v = H[(size_t)i * 128 + c];
        s += v;
        m = fmaxf(m, v);
    }
    ssum[threadIdx.x] = s;
    smax[threadIdx.x] = m;
    __syncthreads();
    if (half == 0) {
        float st = ssum[c] + ssum[c + 128];
        float mt = fmaxf(smax[c], smax[c + 128]);
        float mean = (cn > 0) ? st / (float)cn : 0.f;
        if (cn == 0) mt = 0.f;
        gfeat[g * 256 + c] = mean;
        gfeat[g * 256 + 128 + c] = mt;
    }
}

// ---------------- MLP head ----------------

__global__ __launch_bounds__(128) void k_mlp(const float* __restrict__ gfeat,
                                             const float* __restrict__ Wf1,
                                             const float* __restrict__ bf1,
                                             const float* __restrict__ Wf2,
                                             const float* __restrict__ bf2,
                                             const float* __restrict__ Wf3,
                                             const float* __restrict__ bf3,
                                             float* __restrict__ out) {
    __shared__ float grow[256];
    __shared__ float o1[128];
    __shared__ float o2[64];
    int g = blockIdx.x;
    int t = threadIdx.x;
    grow[t] = gfeat[g * 256 + t];
    grow[t + 128] = gfeat[g * 256 + 128 + t];
    __syncthreads();
    float acc = bf1[t];
#pragma unroll 8
    for (int k = 0; k < 256; k++) acc = fmaf(grow[k], Wf1[k * 128 + t], acc);
    o1[t] = fmaxf(acc, 0.f);
    __syncthreads();
    if (t < 64) {
        float a2 = bf2[t];
#pragma unroll 8
        for (int k = 0; k < 128; k++) a2 = fmaf(o1[k], Wf2[k * 64 + t], a2);
        o2[t] = fmaxf(a2, 0.f);
    }
    __syncthreads();
    if (t < 64) {
        float p = o2[t] * Wf3[t];
        for (int off = 32; off > 0; off >>= 1) p += __shfl_down(p, off);
        if (t == 0) out[g] = p + bf3[0];
    }
}

// ---------------- launch ----------------

extern "C" void kernel_launch(void* const* d_in, const int* in_sizes, int n_in,
                              void* d_out, int out_size, void* d_ws, size_t ws_size,
                              hipStream_t stream) {
    const float* x = (const float*)d_in[0];
    const int* ei = (const int*)d_in[1];
    const int* batch = (const int*)d_in[2];
    // d_in[3] = n_graphs (device scalar); G == out_size since output is [G,1]
    const float* W1 = (const float*)d_in[4];
    const float* b1 = (const float*)d_in[5];
    const float* W2 = (const float*)d_in[6];
    const float* b2 = (const float*)d_in[7];
    const float* W3 = (const float*)d_in[8];
    const float* b3 = (const float*)d_in[9];
    const float* Wf1 = (const float*)d_in[10];
    const float* bf1 = (const float*)d_in[11];
    const float* Wf2 = (const float*)d_in[12];
    const float* bf2 = (const float*)d_in[13];
    const float* Wf3 = (const float*)d_in[14];
    const float* bf3 = (const float*)d_in[15];

    const int N = in_sizes[0] / 128;
    const int E = in_sizes[1] / 2;
    const int G = out_size;

    const int* src = ei;
    const int* dst = ei + E;

    // workspace carve (256B aligned)
    char* w = (char*)d_ws;
    size_t off = 0;
    auto alloc = [&](size_t bytes) -> void* {
        void* p = w + off;
        off += (bytes + 255) / 256 * 256;
        return p;
    };
    unsigned short* U = (unsigned short*)alloc((size_t)N * 128 * 2);  // bf16 message table
    float* H = (float*)alloc((size_t)N * 128 * 4);
    int* csr_src = (int*)alloc((size_t)E * 4);
    int* rowstart = (int*)alloc((size_t)(N + 1) * 4);
    int* cnt = (int*)alloc((size_t)N * 4);
    int* cursor = (int*)alloc((size_t)N * 4);
    float* dinv = (float*)alloc((size_t)N * 4);
    int* part = (int*)alloc(1024 * 4);
    int* boff = (int*)alloc(1024 * 4);
    int* gstart = (int*)alloc((size_t)(G + 1) * 4);
    float* gfeat = (float*)alloc((size_t)G * 256 * 4);
    float* out = (float*)d_out;

    const int nblk = (N + 1023) / 1024;

    hipMemsetAsync(cnt, 0, (size_t)N * 4, stream);
    hipMemsetAsync(cursor, 0, (size_t)N * 4, stream);

    k_count<<<dim3((E + 255) / 256), dim3(256), 0, stream>>>(dst, E, cnt);
    k_scan1<<<dim3(nblk), dim3(256), 0, stream>>>(cnt, N, part);
    k_scan2<<<dim3(1), dim3(1024), 0, stream>>>(part, boff, nblk, rowstart, N, E);
    k_scan3<<<dim3(nblk), dim3(256), 0, stream>>>(cnt, N, boff, rowstart);
    k_dinv<<<dim3((N + 255) / 256), dim3(256), 0, stream>>>(cnt, dinv, N);
    k_fill<<<dim3((E + 255) / 256), dim3(256), 0, stream>>>(src, dst, E, rowstart, cursor,
                                                            csr_src);

    const int gemmGrid = (N + 127) / 128;
    const int aggGrid = (N + 3) / 4;

    // conv1: H = relu(agg(x @ W1) + b1)
    k_gemm<<<dim3(gemmGrid), dim3(256), 0, stream>>>(x, W1, dinv, U, N);
    k_agg<0><<<dim3(aggGrid), dim3(256), 0, stream>>>(U, rowstart, csr_src, dinv, b1, H, N);

    // conv2: H = relu(agg(H @ W2) + b2) + H
    k_gemm<<<dim3(gemmGrid), dim3(256), 0, stream>>>(H, W2, dinv, U, N);
    k_agg<1><<<dim3(aggGrid), dim3(256), 0, stream>>>(U, rowstart, csr_src, dinv, b2, H, N);

    // conv3: H = relu(agg(H @ W3) + b3) + H
    k_gemm<<<dim3(gemmGrid), dim3(256), 0, stream>>>(H, W3, dinv, U, N);
    k_agg<1><<<dim3(aggGrid), dim3(256), 0, stream>>>(U, rowstart, csr_src, dinv, b3, H, N);

    // pooling + head
    k_gstart<<<dim3((G + 256) / 256), dim3(256), 0, stream>>>(batch, N, G, gstart);
    k_pool<<<dim3(G), dim3(256), 0, stream>>>(H, gstart, gfeat);
    k_mlp<<<dim3(G), dim3(128), 0, stream>>>(gfeat, Wf1, bf1, Wf2, bf2, Wf3, bf3, out);
}

// Round 5
// 712.031 us; speedup vs baseline: 1.4780x; 1.0512x over previous
//
#include <hip/hip_runtime.h>
#include <hip/hip_bf16.h>

#define NBMAX 128   // max dst-buckets (N/1024); N=100K -> 98

// ---------------- preprocessing ----------------

__global__ __launch_bounds__(256) void k_count(const int* __restrict__ dst, int E,
                                               int* __restrict__ cnt) {
    int e = blockIdx.x * 256 + threadIdx.x;
    if (e < E) atomicAdd(&cnt[dst[e]], 1);
}

// chunk = 1024 elements per block, thread t owns elements [t*4, t*4+4)
__global__ __launch_bounds__(256) void k_scan1(const int* __restrict__ cnt, int N,
                                               int* __restrict__ part) {
    __shared__ int sh[256];
    int base = blockIdx.x * 1024;
    int t = threadIdx.x;
    int s = 0;
#pragma unroll
    for (int i = 0; i < 4; i++) {
        int idx = base + t * 4 + i;
        if (idx < N) s += cnt[idx];
    }
    sh[t] = s;
    __syncthreads();
    for (int off = 128; off > 0; off >>= 1) {
        if (t < off) sh[t] += sh[t + off];
        __syncthreads();
    }
    if (t == 0) part[blockIdx.x] = sh[0];
}

__global__ __launch_bounds__(1024) void k_scan2(const int* __restrict__ part,
                                                int* __restrict__ boff, int nblk,
                                                int* __restrict__ rowstart, int N, int E) {
    __shared__ int sh[1024];
    int t = threadIdx.x;
    int v = (t < nblk) ? part[t] : 0;
    sh[t] = v;
    __syncthreads();
    for (int off = 1; off < 1024; off <<= 1) {
        int x = (t >= off) ? sh[t - off] : 0;
        __syncthreads();
        sh[t] += x;
        __syncthreads();
    }
    if (t < nblk) boff[t] = sh[t] - v;  // exclusive
    if (t == 0) rowstart[N] = E;
}

__global__ __launch_bounds__(256) void k_scan3(const int* __restrict__ cnt, int N,
                                               const int* __restrict__ boff,
                                               int* __restrict__ rowstart) {
    __shared__ int sh[256];
    int base = blockIdx.x * 1024;
    int t = threadIdx.x;
    int idx = base + t * 4;
    int v0 = 0, v1 = 0, v2 = 0, v3 = 0;
    if (idx + 3 < N) {
        int4 q = *(const int4*)&cnt[idx];
        v0 = q.x; v1 = q.y; v2 = q.z; v3 = q.w;
    } else {
        if (idx < N) v0 = cnt[idx];
        if (idx + 1 < N) v1 = cnt[idx + 1];
        if (idx + 2 < N) v2 = cnt[idx + 2];
        if (idx + 3 < N) v3 = cnt[idx + 3];
    }
    int tot = v0 + v1 + v2 + v3;
    sh[t] = tot;
    __syncthreads();
    for (int off = 1; off < 256; off <<= 1) {
        int x = (t >= off) ? sh[t - off] : 0;
        __syncthreads();
        sh[t] += x;
        __syncthreads();
    }
    int excl = sh[t] - tot;
    int b0 = boff[blockIdx.x] + excl;
    if (idx + 3 < N) {
        int4 w = make_int4(b0, b0 + v0, b0 + v0 + v1, b0 + v0 + v1 + v2);
        *(int4*)&rowstart[idx] = w;
    } else {
        if (idx < N) rowstart[idx] = b0;
        if (idx + 1 < N) rowstart[idx + 1] = b0 + v0;
        if (idx + 2 < N) rowstart[idx + 2] = b0 + v0 + v1;
        if (idx + 3 < N) rowstart[idx + 3] = b0 + v0 + v1 + v2;
    }
}

__global__ __launch_bounds__(256) void k_dinv(const int* __restrict__ cnt,
                                              float* __restrict__ dinv, int N) {
    int n = blockIdx.x * 256 + threadIdx.x;
    if (n < N) dinv[n] = rsqrtf((float)cnt[n] + 1.0f);  // deg = in-edges + self-loop
}

// bucket cursors start at each bucket's CSR segment start
__global__ __launch_bounds__(128) void k_binit(const int* __restrict__ rowstart, int N, int NB,
                                               int* __restrict__ bcur) {
    int b = blockIdx.x * 128 + threadIdx.x;
    if (b < NB) bcur[b] = rowstart[min(b << 10, N)];
}

// pass 1: bucket-sort edges by dst>>10 into pairs[] (CSR-region-ordered).
// LDS histogram per 4096-edge chunk -> one global atomic per (block,bucket) ->
// contiguous ~340B runs per bucket: full-line writebacks instead of 4B scatter.
__global__ __launch_bounds__(256) void k_bucket(const int* __restrict__ src,
                                                const int* __restrict__ dst, int E, int NB,
                                                int* __restrict__ bcur,
                                                uint2* __restrict__ pairs) {
    __shared__ int lcnt[NBMAX];
    __shared__ int gbase[NBMAX];
    int t = threadIdx.x;
    int base = blockIdx.x * 4096;
    for (int i = t; i < NB; i += 256) lcnt[i] = 0;
    __syncthreads();
    int rank[16];
#pragma unroll
    for (int i = 0; i < 16; i++) {
        int e = base + i * 256 + t;
        rank[i] = (e < E) ? atomicAdd(&lcnt[dst[e] >> 10], 1) : -1;
    }
    __syncthreads();
    for (int i = t; i < NB; i += 256) {
        int c = lcnt[i];
        gbase[i] = c ? atomicAdd(&bcur[i], c) : 0;
    }
    __syncthreads();
#pragma unroll
    for (int i = 0; i < 16; i++) {
        int e = base + i * 256 + t;
        if (e < E) {
            int d = dst[e];
            pairs[gbase[d >> 10] + rank[i]] = make_uint2((unsigned)src[e], (unsigned)d);
        }
    }
}

// pass 2: one block per bucket (1024 dst nodes). Ranks via LDS atomics (each dst
// is owned by exactly one block); csr_src writes land in a ~65KB L2-local region.
__global__ __launch_bounds__(256) void k_place(const uint2* __restrict__ pairs,
                                               const int* __restrict__ rowstart, int N,
                                               int* __restrict__ csr_src) {
    __shared__ int cur[1024];
    int t = threadIdx.x;
    int n0 = blockIdx.x << 10;
    int n1 = min(N, n0 + 1024);
    for (int i = t; i < 1024; i += 256) cur[i] = 0;
    __syncthreads();
    int e0 = rowstart[n0], e1 = rowstart[n1];
    for (int e = e0 + t; e < e1; e += 256) {
        uint2 p = pairs[e];
        int d = (int)p.y;
        int r = atomicAdd(&cur[d - n0], 1);
        csr_src[rowstart[d] + r] = (int)p.x;
    }
}

// ---- bf16 pack/unpack helpers (RNE) ----
__device__ inline unsigned pack_bf16_pair(float lo, float hi) {
    unsigned ul = __float_as_uint(lo);
    unsigned uh = __float_as_uint(hi);
    ul = (ul + 0x7FFFu + ((ul >> 16) & 1u)) >> 16;
    uh = (uh + 0x7FFFu + ((uh >> 16) & 1u)) & 0xFFFF0000u;
    return ul | uh;
}

__device__ inline float4 unpack_bf16_quad(uint2 q) {
    float4 r;
    r.x = __uint_as_float(q.x << 16);
    r.y = __uint_as_float(q.x & 0xFFFF0000u);
    r.z = __uint_as_float(q.y << 16);
    r.w = __uint_as_float(q.y & 0xFFFF0000u);
    return r;
}

// ---------------- GEMM: U = bf16(dinv .* (A @ W))  (A:[N,128] f32, W:[128,128]) ----
// 128x128 tile per block, 256 threads, 8x8 per thread, fp32 accumulate.
// Epilogue scales row r by dinv[r] and stores bf16 (one RNE rounding per element):
//   sum_e dinv_s*dinv_d*T_s = dinv_d * sum_e U_s,  U = dinv .* T.

__global__ __launch_bounds__(256) void k_gemm(const float* __restrict__ A,
                                              const float* __restrict__ W,
                                              const float* __restrict__ dinv,
                                              unsigned short* __restrict__ U, int N) {
    __shared__ float AshT[32][132];  // [k][row], pad 132 for transpose-store
    __shared__ float Wsh[32][132];   // [k][col]
    int t = threadIdx.x;
    int tr = t >> 4;        // 0..15
    int tc = t & 15;        // 0..15
    int rowBase = blockIdx.x * 128;
    float acc[8][8] = {};

    for (int kc = 0; kc < 4; kc++) {
#pragma unroll
        for (int i = 0; i < 4; i++) {
            int q = t + i * 256;     // float4 id, 0..1023
            int row = q >> 3;        // 0..127
            int c4 = q & 7;          // 0..7
            int gr = rowBase + row;
            float4 a4 = make_float4(0.f, 0.f, 0.f, 0.f);
            if (gr < N) a4 = *(const float4*)&A[(size_t)gr * 128 + kc * 32 + c4 * 4];
            AshT[c4 * 4 + 0][row] = a4.x;
            AshT[c4 * 4 + 1][row] = a4.y;
            AshT[c4 * 4 + 2][row] = a4.z;
            AshT[c4 * 4 + 3][row] = a4.w;
        }
#pragma unroll
        for (int i = 0; i < 4; i++) {
            int q = t + i * 256;     // 0..1023
            int k = q >> 5;          // 0..31
            int c4 = q & 31;         // 0..31
            float4 w4 = *(const float4*)&W[(size_t)(kc * 32 + k) * 128 + c4 * 4];
            *(float4*)&Wsh[k][c4 * 4] = w4;
        }
        __syncthreads();
#pragma unroll
        for (int k = 0; k < 32; k++) {
            float4 a0 = *(const float4*)&AshT[k][tr * 8];
            float4 a1 = *(const float4*)&AshT[k][tr * 8 + 4];
            float4 w0 = *(const float4*)&Wsh[k][tc * 8];
            float4 w1 = *(const float4*)&Wsh[k][tc * 8 + 4];
            float a[8] = {a0.x, a0.y, a0.z, a0.w, a1.x, a1.y, a1.z, a1.w};
            float w[8] = {w0.x, w0.y, w0.z, w0.w, w1.x, w1.y, w1.z, w1.w};
#pragma unroll
            for (int i = 0; i < 8; i++)
#pragma unroll
                for (int j = 0; j < 8; j++) acc[i][j] = fmaf(a[i], w[j], acc[i][j]);
        }
        __syncthreads();
    }
#pragma unroll
    for (int i = 0; i < 8; i++) {
        int gr = rowBase + tr * 8 + i;
        if (gr < N) {
            float dv = dinv[gr];
            uint4 p;
            p.x = pack_bf16_pair(dv * acc[i][0], dv * acc[i][1]);
            p.y = pack_bf16_pair(dv * acc[i][2], dv * acc[i][3]);
            p.z = pack_bf16_pair(dv * acc[i][4], dv * acc[i][5]);
            p.w = pack_bf16_pair(dv * acc[i][6], dv * acc[i][7]);
            *(uint4*)&U[(size_t)gr * 128 + tc * 8] = p;
        }
    }
}

// ---------------- aggregation ----------------
// H[n] = relu(dinv[n] * (U[n] + sum_{e in CSR(n)} U[src_e]) + bias) (+ H[n] if RES)
// One wave per node; two 32-lane groups own contiguous halves of the edge list.
// U rows are bf16 (256B): lane l loads 8B (channels l*4..l*4+3), fp32 accumulate.

template <int RES>
__global__ __launch_bounds__(256) void k_agg(const unsigned short* __restrict__ U,
                                             const int* __restrict__ rowstart,
                                             const int* __restrict__ csr_src,
                                             const float* __restrict__ dinv,
                                             const float* __restrict__ bias,
                                             float* __restrict__ H, int N) {
    int wave = threadIdx.x >> 6;  // 0..3
    int lane = threadIdx.x & 63;
    int n = blockIdx.x * 4 + wave;
    if (n >= N) return;
    int g = lane >> 5;   // edge group 0/1
    int l = lane & 31;   // channel quad: channels l*4 .. l*4+3
    int e0 = rowstart[n], e1 = rowstart[n + 1];
    int half = (e1 - e0) >> 1;
    int a0 = g ? (e0 + half) : e0;
    int a1 = g ? e1 : (e0 + half);

    float4 A0 = {0.f, 0.f, 0.f, 0.f};
    float4 A1 = {0.f, 0.f, 0.f, 0.f};
    float4 A2 = {0.f, 0.f, 0.f, 0.f};
    float4 A3 = {0.f, 0.f, 0.f, 0.f};

    int e = a0;
    for (; e + 4 <= a1; e += 4) {
        int s0 = csr_src[e], s1 = csr_src[e + 1];
        int s2 = csr_src[e + 2], s3 = csr_src[e + 3];
        uint2 q0 = *(const uint2*)&U[(size_t)s0 * 128 + l * 4];
        uint2 q1 = *(const uint2*)&U[(size_t)s1 * 128 + l * 4];
        uint2 q2 = *(const uint2*)&U[(size_t)s2 * 128 + l * 4];
        uint2 q3 = *(const uint2*)&U[(size_t)s3 * 128 + l * 4];
        float4 r0 = unpack_bf16_quad(q0);
        float4 r1 = unpack_bf16_quad(q1);
        float4 r2 = unpack_bf16_quad(q2);
        float4 r3 = unpack_bf16_quad(q3);
        A0.x += r0.x; A0.y += r0.y; A0.z += r0.z; A0.w += r0.w;
        A1.x += r1.x; A1.y += r1.y; A1.z += r1.z; A1.w += r1.w;
        A2.x += r2.x; A2.y += r2.y; A2.z += r2.z; A2.w += r2.w;
        A3.x += r3.x; A3.y += r3.y; A3.z += r3.z; A3.w += r3.w;
    }
    for (; e < a1; e++) {
        int s = csr_src[e];
        uint2 q = *(const uint2*)&U[(size_t)s * 128 + l * 4];
        float4 r = unpack_bf16_quad(q);
        A0.x += r.x; A0.y += r.y; A0.z += r.z; A0.w += r.w;
    }

    float ax = (A0.x + A1.x) + (A2.x + A3.x);
    float ay = (A0.y + A1.y) + (A2.y + A3.y);
    float az = (A0.z + A1.z) + (A2.z + A3.z);
    float aw = (A0.w + A1.w) + (A2.w + A3.w);

    // combine the two groups (xor 32 sums both halves into every lane)
    ax += __shfl_xor(ax, 32);
    ay += __shfl_xor(ay, 32);
    az += __shfl_xor(az, 32);
    aw += __shfl_xor(aw, 32);

    if (g == 0) {
        uint2 qs = *(const uint2*)&U[(size_t)n * 128 + l * 4];
        float4 self = unpack_bf16_quad(qs);
        float4 bi = *(const float4*)&bias[l * 4];
        float dn = dinv[n];
        float4 out;
        out.x = fmaxf(dn * (ax + self.x) + bi.x, 0.f);
        out.y = fmaxf(dn * (ay + self.y) + bi.y, 0.f);
        out.z = fmaxf(dn * (az + self.z) + bi.z, 0.f);
        out.w = fmaxf(dn * (aw + self.w) + bi.w, 0.f);
        if (RES) {
            float4 h = *(const float4*)&H[(size_t)n * 128 + l * 4];
            out.x += h.x; out.y += h.y; out.z += h.z; out.w += h.w;
        }
        *(float4*)&H[(size_t)n * 128 + l * 4] = out;
    }
}

// ---------------- pooling ----------------

__global__ __launch_bounds__(256) void k_gstart(const int* __restrict__ batch, int N, int G,
                                                int* __restrict__ gstart) {
    int g = blockIdx.x * 256 + threadIdx.x;
    if (g > G) return;
    if (g == G) { gstart[g] = N; return; }
    int lo = 0, hi = N;
    while (lo < hi) {
        int mid = (lo + hi) >> 1;
        if (batch[mid] < g) lo = mid + 1; else hi = mid;
    }
    gstart[g] = lo;
}

// one block (256 threads) per graph; two halves of the node range in parallel
__global__ __launch_bounds__(256) void k_pool(const float* __restrict__ H,
                                              const int* __restrict__ gstart,
                                              float* __restrict__ gfeat) {
    __shared__ float ssum[256];
    __shared__ float smax[256];
    int g = blockIdx.x;
    int c = threadIdx.x & 127;
    int half = threadIdx.x >> 7;
    int i0 = gstart[g], i1 = gstart[g + 1];
    int cn = i1 - i0;
    int mid = i0 + (cn >> 1);
    int a0 = half ? mid : i0;
    int a1 = half ? i1 : mid;
    float s = 0.f, m = -3.4e38f;
    for (int i = a0; i < a1; i++) {
        float v = H[(size_t)i * 128 + c];
        s += v;
        m = fmaxf(m, v);
    }
    ssum[threadIdx.x] = s;
    smax[threadIdx.x] = m;
    __syncthreads();
    if (half == 0) {
        float st = ssum[c] + ssum[c + 128];
        float mt = fmaxf(smax[c], smax[c + 128]);
        float mean = (cn > 0) ? st / (float)cn : 0.f;
        if (cn == 0) mt = 0.f;
        gfeat[g * 256 + c] = mean;
        gfeat[g * 256 + 128 + c] = mt;
    }
}

// ---------------- MLP head ----------------

__global__ __launch_bounds__(128) void k_mlp(const float* __restrict__ gfeat,
                                             const float* __restrict__ Wf1,
                                             const float* __restrict__ bf1,
                                             const float* __restrict__ Wf2,
                                             const float* __restrict__ bf2,
                                             const float* __restrict__ Wf3,
                                             const float* __restrict__ bf3,
                                             float* __restrict__ out) {
    __shared__ float grow[256];
    __shared__ float o1[128];
    __shared__ float o2[64];
    int g = blockIdx.x;
    int t = threadIdx.x;
    grow[t] = gfeat[g * 256 + t];
    grow[t + 128] = gfeat[g * 256 + 128 + t];
    __syncthreads();
    float acc = bf1[t];
#pragma unroll 8
    for (int k = 0; k < 256; k++) acc = fmaf(grow[k], Wf1[k * 128 + t], acc);
    o1[t] = fmaxf(acc, 0.f);
    __syncthreads();
    if (t < 64) {
        float a2 = bf2[t];
#pragma unroll 8
        for (int k = 0; k < 128; k++) a2 = fmaf(o1[k], Wf2[k * 64 + t], a2);
        o2[t] = fmaxf(a2, 0.f);
    }
    __syncthreads();
    if (t < 64) {
        float p = o2[t] * Wf3[t];
        for (int off = 32; off > 0; off >>= 1) p += __shfl_down(p, off);
        if (t == 0) out[g] = p + bf3[0];
    }
}

// ---------------- launch ----------------

extern "C" void kernel_launch(void* const* d_in, const int* in_sizes, int n_in,
                              void* d_out, int out_size, void* d_ws, size_t ws_size,
                              hipStream_t stream) {
    const float* x = (const float*)d_in[0];
    const int* ei = (const int*)d_in[1];
    const int* batch = (const int*)d_in[2];
    // d_in[3] = n_graphs (device scalar); G == out_size since output is [G,1]
    const float* W1 = (const float*)d_in[4];
    const float* b1 = (const float*)d_in[5];
    const float* W2 = (const float*)d_in[6];
    const float* b2 = (const float*)d_in[7];
    const float* W3 = (const float*)d_in[8];
    const float* b3 = (const float*)d_in[9];
    const float* Wf1 = (const float*)d_in[10];
    const float* bf1 = (const float*)d_in[11];
    const float* Wf2 = (const float*)d_in[12];
    const float* bf2 = (const float*)d_in[13];
    const float* Wf3 = (const float*)d_in[14];
    const float* bf3 = (const float*)d_in[15];

    const int N = in_sizes[0] / 128;
    const int E = in_sizes[1] / 2;
    const int G = out_size;

    const int* src = ei;
    const int* dst = ei + E;

    // workspace carve (256B aligned)
    char* w = (char*)d_ws;
    size_t off = 0;
    auto alloc = [&](size_t bytes) -> void* {
        void* p = w + off;
        off += (bytes + 255) / 256 * 256;
        return p;
    };
    unsigned short* U = (unsigned short*)alloc((size_t)N * 128 * 2);  // bf16 message table
    float* H = (float*)alloc((size_t)N * 128 * 4);
    uint2* pairs = (uint2*)alloc((size_t)E * 8);   // bucket-sorted (src,dst)
    int* csr_src = (int*)alloc((size_t)E * 4);
    int* rowstart = (int*)alloc((size_t)(N + 1) * 4);
    int* cnt = (int*)alloc((size_t)N * 4);
    int* bcur = (int*)alloc(NBMAX * 4);
    float* dinv = (float*)alloc((size_t)N * 4);
    int* part = (int*)alloc(1024 * 4);
    int* boff = (int*)alloc(1024 * 4);
    int* gstart = (int*)alloc((size_t)(G + 1) * 4);
    float* gfeat = (float*)alloc((size_t)G * 256 * 4);
    float* out = (float*)d_out;

    const int nblk = (N + 1023) / 1024;
    const int NB = (N + 1023) >> 10;

    hipMemsetAsync(cnt, 0, (size_t)N * 4, stream);

    k_count<<<dim3((E + 255) / 256), dim3(256), 0, stream>>>(dst, E, cnt);
    k_scan1<<<dim3(nblk), dim3(256), 0, stream>>>(cnt, N, part);
    k_scan2<<<dim3(1), dim3(1024), 0, stream>>>(part, boff, nblk, rowstart, N, E);
    k_scan3<<<dim3(nblk), dim3(256), 0, stream>>>(cnt, N, boff, rowstart);
    k_dinv<<<dim3((N + 255) / 256), dim3(256), 0, stream>>>(cnt, dinv, N);
    k_binit<<<dim3((NB + 127) / 128), dim3(128), 0, stream>>>(rowstart, N, NB, bcur);
    k_bucket<<<dim3((E + 4095) / 4096), dim3(256), 0, stream>>>(src, dst, E, NB, bcur, pairs);
    k_place<<<dim3(NB), dim3(256), 0, stream>>>(pairs, rowstart, N, csr_src);

    const int gemmGrid = (N + 127) / 128;
    const int aggGrid = (N + 3) / 4;

    // conv1: H = relu(agg(x @ W1) + b1)
    k_gemm<<<dim3(gemmGrid), dim3(256), 0, stream>>>(x, W1, dinv, U, N);
    k_agg<0><<<dim3(aggGrid), dim3(256), 0, stream>>>(U, rowstart, csr_src, dinv, b1, H, N);

    // conv2: H = relu(agg(H @ W2) + b2) + H
    k_gemm<<<dim3(gemmGrid), dim3(256), 0, stream>>>(H, W2, dinv, U, N);
    k_agg<1><<<dim3(aggGrid), dim3(256), 0, stream>>>(U, rowstart, csr_src, dinv, b2, H, N);

    // conv3: H = relu(agg(H @ W3) + b3) + H
    k_gemm<<<dim3(gemmGrid), dim3(256), 0, stream>>>(H, W3, dinv, U, N);
    k_agg<1><<<dim3(aggGrid), dim3(256), 0, stream>>>(U, rowstart, csr_src, dinv, b3, H, N);

    // pooling + head
    k_gstart<<<dim3((G + 256) / 256), dim3(256), 0, stream>>>(batch, N, G, gstart);
    k_pool<<<dim3(G), dim3(256), 0, stream>>>(H, gstart, gfeat);
    k_mlp<<<dim3(G), dim3(128), 0, stream>>>(gfeat, Wf1, bf1, Wf2, bf2, Wf3, bf3, out);
}

// Round 6
// 615.546 us; speedup vs baseline: 1.7097x; 1.1567x over previous
//
#include <hip/hip_runtime.h>
#include <hip/hip_bf16.h>

#define NBMAX 128   // max dst-buckets (N/1024); N=100K -> 98

typedef __attribute__((ext_vector_type(8))) short short8;   // 8 bf16 (4 VGPR) MFMA operand
typedef __attribute__((ext_vector_type(4))) float f32x4;    // MFMA accumulator

// ---- bf16 helpers (RNE) ----
__device__ inline unsigned short bf16_rne(float x) {
    unsigned u = __float_as_uint(x);
    u = (u + 0x7FFFu + ((u >> 16) & 1u)) >> 16;
    return (unsigned short)u;
}
__device__ inline float bf16_to_f(unsigned short h) {
    return __uint_as_float(((unsigned)h) << 16);
}
__device__ inline void split2(float v, short& h, short& lo) {
    unsigned short hb = bf16_rne(v);
    h = (short)hb;
    lo = (short)bf16_rne(v - bf16_to_f(hb));
}
__device__ inline unsigned pack_bf16_pair(float lo, float hi) {
    unsigned ul = __float_as_uint(lo);
    unsigned uh = __float_as_uint(hi);
    ul = (ul + 0x7FFFu + ((ul >> 16) & 1u)) >> 16;
    uh = (uh + 0x7FFFu + ((uh >> 16) & 1u)) & 0xFFFF0000u;
    return ul | uh;
}
__device__ inline float4 unpack_bf16_quad(uint2 q) {
    float4 r;
    r.x = __uint_as_float(q.x << 16);
    r.y = __uint_as_float(q.x & 0xFFFF0000u);
    r.z = __uint_as_float(q.y << 16);
    r.w = __uint_as_float(q.y & 0xFFFF0000u);
    return r;
}

// ---------------- preprocessing ----------------

__global__ __launch_bounds__(256) void k_count(const int* __restrict__ dst, int E,
                                               int* __restrict__ cnt) {
    int e = blockIdx.x * 256 + threadIdx.x;
    if (e < E) atomicAdd(&cnt[dst[e]], 1);
}

__global__ __launch_bounds__(256) void k_scan1(const int* __restrict__ cnt, int N,
                                               int* __restrict__ part) {
    __shared__ int sh[256];
    int base = blockIdx.x * 1024;
    int t = threadIdx.x;
    int s = 0;
#pragma unroll
    for (int i = 0; i < 4; i++) {
        int idx = base + t * 4 + i;
        if (idx < N) s += cnt[idx];
    }
    sh[t] = s;
    __syncthreads();
    for (int off = 128; off > 0; off >>= 1) {
        if (t < off) sh[t] += sh[t + off];
        __syncthreads();
    }
    if (t == 0) part[blockIdx.x] = sh[0];
}

__global__ __launch_bounds__(1024) void k_scan2(const int* __restrict__ part,
                                                int* __restrict__ boff, int nblk,
                                                int* __restrict__ rowstart, int N, int E) {
    __shared__ int sh[1024];
    int t = threadIdx.x;
    int v = (t < nblk) ? part[t] : 0;
    sh[t] = v;
    __syncthreads();
    for (int off = 1; off < 1024; off <<= 1) {
        int x = (t >= off) ? sh[t - off] : 0;
        __syncthreads();
        sh[t] += x;
        __syncthreads();
    }
    if (t < nblk) boff[t] = sh[t] - v;  // exclusive
    if (t == 0) rowstart[N] = E;
}

__global__ __launch_bounds__(256) void k_scan3(const int* __restrict__ cnt, int N,
                                               const int* __restrict__ boff,
                                               int* __restrict__ rowstart) {
    __shared__ int sh[256];
    int base = blockIdx.x * 1024;
    int t = threadIdx.x;
    int idx = base + t * 4;
    int v0 = 0, v1 = 0, v2 = 0, v3 = 0;
    if (idx + 3 < N) {
        int4 q = *(const int4*)&cnt[idx];
        v0 = q.x; v1 = q.y; v2 = q.z; v3 = q.w;
    } else {
        if (idx < N) v0 = cnt[idx];
        if (idx + 1 < N) v1 = cnt[idx + 1];
        if (idx + 2 < N) v2 = cnt[idx + 2];
        if (idx + 3 < N) v3 = cnt[idx + 3];
    }
    int tot = v0 + v1 + v2 + v3;
    sh[t] = tot;
    __syncthreads();
    for (int off = 1; off < 256; off <<= 1) {
        int x = (t >= off) ? sh[t - off] : 0;
        __syncthreads();
        sh[t] += x;
        __syncthreads();
    }
    int excl = sh[t] - tot;
    int b0 = boff[blockIdx.x] + excl;
    if (idx + 3 < N) {
        int4 w = make_int4(b0, b0 + v0, b0 + v0 + v1, b0 + v0 + v1 + v2);
        *(int4*)&rowstart[idx] = w;
    } else {
        if (idx < N) rowstart[idx] = b0;
        if (idx + 1 < N) rowstart[idx + 1] = b0 + v0;
        if (idx + 2 < N) rowstart[idx + 2] = b0 + v0 + v1;
        if (idx + 3 < N) rowstart[idx + 3] = b0 + v0 + v1 + v2;
    }
}

__global__ __launch_bounds__(256) void k_dinv(const int* __restrict__ cnt,
                                              float* __restrict__ dinv, int N) {
    int n = blockIdx.x * 256 + threadIdx.x;
    if (n < N) dinv[n] = rsqrtf((float)cnt[n] + 1.0f);  // deg = in-edges + self-loop
}

// bucket cursors start at each bucket's CSR segment start
__global__ __launch_bounds__(128) void k_binit(const int* __restrict__ rowstart, int N, int NB,
                                               int* __restrict__ bcur) {
    int b = blockIdx.x * 128 + threadIdx.x;
    if (b < NB) bcur[b] = rowstart[min(b << 10, N)];
}

// pass 1: bucket-sort edges by dst>>10 into pairs[] (CSR-region-ordered).
__global__ __launch_bounds__(256) void k_bucket(const int* __restrict__ src,
                                                const int* __restrict__ dst, int E, int NB,
                                                int* __restrict__ bcur,
                                                uint2* __restrict__ pairs) {
    __shared__ int lcnt[NBMAX];
    __shared__ int gbase[NBMAX];
    int t = threadIdx.x;
    int base = blockIdx.x * 4096;
    for (int i = t; i < NB; i += 256) lcnt[i] = 0;
    __syncthreads();
    int rank[16];
#pragma unroll
    for (int i = 0; i < 16; i++) {
        int e = base + i * 256 + t;
        rank[i] = (e < E) ? atomicAdd(&lcnt[dst[e] >> 10], 1) : -1;
    }
    __syncthreads();
    for (int i = t; i < NB; i += 256) {
        int c = lcnt[i];
        gbase[i] = c ? atomicAdd(&bcur[i], c) : 0;
    }
    __syncthreads();
#pragma unroll
    for (int i = 0; i < 16; i++) {
        int e = base + i * 256 + t;
        if (e < E) {
            int d = dst[e];
            pairs[gbase[d >> 10] + rank[i]] = make_uint2((unsigned)src[e], (unsigned)d);
        }
    }
}

// pass 2: one block per bucket (1024 dst nodes); ranks via LDS atomics.
__global__ __launch_bounds__(256) void k_place(const uint2* __restrict__ pairs,
                                               const int* __restrict__ rowstart, int N,
                                               int* __restrict__ csr_src) {
    __shared__ int cur[1024];
    int t = threadIdx.x;
    int n0 = blockIdx.x << 10;
    int n1 = min(N, n0 + 1024);
    for (int i = t; i < 1024; i += 256) cur[i] = 0;
    __syncthreads();
    int e0 = rowstart[n0], e1 = rowstart[n1];
    for (int e = e0 + t; e < e1; e += 256) {
        uint2 p = pairs[e];
        int d = (int)p.y;
        int r = atomicAdd(&cur[d - n0], 1);
        csr_src[rowstart[d] + r] = (int)p.x;
    }
}

// ---------------- W prep: fragment-ordered bf16 hi/lo ----------------
// Target layout: frag[((kc*8 + colTile)*64 + lane)*8 + j], where the element is
// W[k = kc*32 + (lane>>4)*8 + j][col = colTile*16 + (lane&15)]  (W is [128][128] row-major).
__global__ __launch_bounds__(256) void k_wprep(const float* __restrict__ W,
                                               unsigned short* __restrict__ WH,
                                               unsigned short* __restrict__ WL) {
    int idx = blockIdx.x * 256 + threadIdx.x;  // 0..16383
    int j = idx & 7;
    int lane = (idx >> 3) & 63;
    int ct = (idx >> 9) & 7;
    int kc = idx >> 12;
    int k = kc * 32 + (lane >> 4) * 8 + j;
    int col = ct * 16 + (lane & 15);
    float v = W[k * 128 + col];
    unsigned short hb = bf16_rne(v);
    WH[idx] = hb;
    WL[idx] = bf16_rne(v - bf16_to_f(hb));
}

// ---------------- GEMM: U = bf16(dinv .* (A @ W)) via 3-term bf16 MFMA ----------
// A*W ~= Ah*Wh + Ah*Wl + Al*Wh  (each X = Xh + Xl, Xh=bf16(X), Xl=bf16(X-Xh))
// carries ~16 mantissa bits -> error far below the bf16-U storage rounding.
// Block = 128 rows; wave w owns rows [blk*128 + w*32, +32) = 2 rowTiles of 16.
// No LDS, no syncthreads: A frags loaded per-lane from global, W frags from
// the pre-converted fragment-ordered arrays (L1/L2-resident, coalesced 16B/lane).

__global__ __launch_bounds__(256) void k_gemm3(const float* __restrict__ A,
                                               const unsigned short* __restrict__ WH,
                                               const unsigned short* __restrict__ WL,
                                               const float* __restrict__ dinv,
                                               unsigned short* __restrict__ U, int N) {
    int wv = threadIdx.x >> 6;
    int l = threadIdx.x & 63;
    int quad = l >> 4;
    int lm = l & 15;
    int rowBase = blockIdx.x * 128 + wv * 32;

    f32x4 acc[2][8] = {};

    int r0 = rowBase + lm;        // rowTile 0: A[m=lane&15][k=quad*8+j]
    int r1 = rowBase + 16 + lm;   // rowTile 1

    for (int kc = 0; kc < 4; kc++) {
        int k0 = kc * 32 + quad * 8;
        float av0[8] = {}, av1[8] = {};
        if (r0 < N) {
            float4 a = *(const float4*)&A[(size_t)r0 * 128 + k0];
            float4 b = *(const float4*)&A[(size_t)r0 * 128 + k0 + 4];
            av0[0] = a.x; av0[1] = a.y; av0[2] = a.z; av0[3] = a.w;
            av0[4] = b.x; av0[5] = b.y; av0[6] = b.z; av0[7] = b.w;
        }
        if (r1 < N) {
            float4 a = *(const float4*)&A[(size_t)r1 * 128 + k0];
            float4 b = *(const float4*)&A[(size_t)r1 * 128 + k0 + 4];
            av1[0] = a.x; av1[1] = a.y; av1[2] = a.z; av1[3] = a.w;
            av1[4] = b.x; av1[5] = b.y; av1[6] = b.z; av1[7] = b.w;
        }
        short8 ah0, al0, ah1, al1;
#pragma unroll
        for (int j = 0; j < 8; j++) {
            short h, lo;
            split2(av0[j], h, lo); ah0[j] = h; al0[j] = lo;
            split2(av1[j], h, lo); ah1[j] = h; al1[j] = lo;
        }
#pragma unroll
        for (int ct = 0; ct < 8; ct++) {
            size_t fo = ((size_t)(kc * 8 + ct) * 64 + l) * 8;
            short8 wh = *(const short8*)&WH[fo];
            short8 wl = *(const short8*)&WL[fo];
            acc[0][ct] = __builtin_amdgcn_mfma_f32_16x16x32_bf16(ah0, wh, acc[0][ct], 0, 0, 0);
            acc[0][ct] = __builtin_amdgcn_mfma_f32_16x16x32_bf16(ah0, wl, acc[0][ct], 0, 0, 0);
            acc[0][ct] = __builtin_amdgcn_mfma_f32_16x16x32_bf16(al0, wh, acc[0][ct], 0, 0, 0);
            acc[1][ct] = __builtin_amdgcn_mfma_f32_16x16x32_bf16(ah1, wh, acc[1][ct], 0, 0, 0);
            acc[1][ct] = __builtin_amdgcn_mfma_f32_16x16x32_bf16(ah1, wl, acc[1][ct], 0, 0, 0);
            acc[1][ct] = __builtin_amdgcn_mfma_f32_16x16x32_bf16(al1, wh, acc[1][ct], 0, 0, 0);
        }
    }

    // epilogue: C/D map col=lane&15, row=quad*4+reg (m89-verified)
#pragma unroll
    for (int rt = 0; rt < 2; rt++) {
#pragma unroll
        for (int reg = 0; reg < 4; reg++) {
            int row = rowBase + rt * 16 + quad * 4 + reg;
            if (row < N) {
                float dv = dinv[row];
#pragma unroll
                for (int ct = 0; ct < 8; ct++) {
                    U[(size_t)row * 128 + ct * 16 + lm] = bf16_rne(dv * acc[rt][ct][reg]);
                }
            }
        }
    }
}

// ---------------- aggregation ----------------
// H[n] = relu(dinv[n] * (U[n] + sum_{e in CSR(n)} U[src_e]) + bias) (+ H[n] if RES)

template <int RES>
__global__ __launch_bounds__(256) void k_agg(const unsigned short* __restrict__ U,
                                             const int* __restrict__ rowstart,
                                             const int* __restrict__ csr_src,
                                             const float* __restrict__ dinv,
                                             const float* __restrict__ bias,
                                             float* __restrict__ H, int N) {
    int wave = threadIdx.x >> 6;  // 0..3
    int lane = threadIdx.x & 63;
    int n = blockIdx.x * 4 + wave;
    if (n >= N) return;
    int g = lane >> 5;   // edge group 0/1
    int l = lane & 31;   // channel quad: channels l*4 .. l*4+3
    int e0 = rowstart[n], e1 = rowstart[n + 1];
    int half = (e1 - e0) >> 1;
    int a0 = g ? (e0 + half) : e0;
    int a1 = g ? e1 : (e0 + half);

    float4 A0 = {0.f, 0.f, 0.f, 0.f};
    float4 A1 = {0.f, 0.f, 0.f, 0.f};
    float4 A2 = {0.f, 0.f, 0.f, 0.f};
    float4 A3 = {0.f, 0.f, 0.f, 0.f};

    int e = a0;
    for (; e + 4 <= a1; e += 4) {
        int s0 = csr_src[e], s1 = csr_src[e + 1];
        int s2 = csr_src[e + 2], s3 = csr_src[e + 3];
        uint2 q0 = *(const uint2*)&U[(size_t)s0 * 128 + l * 4];
        uint2 q1 = *(const uint2*)&U[(size_t)s1 * 128 + l * 4];
        uint2 q2 = *(const uint2*)&U[(size_t)s2 * 128 + l * 4];
        uint2 q3 = *(const uint2*)&U[(size_t)s3 * 128 + l * 4];
        float4 r0 = unpack_bf16_quad(q0);
        float4 r1 = unpack_bf16_quad(q1);
        float4 r2 = unpack_bf16_quad(q2);
        float4 r3 = unpack_bf16_quad(q3);
        A0.x += r0.x; A0.y += r0.y; A0.z += r0.z; A0.w += r0.w;
        A1.x += r1.x; A1.y += r1.y; A1.z += r1.z; A1.w += r1.w;
        A2.x += r2.x; A2.y += r2.y; A2.z += r2.z; A2.w += r2.w;
        A3.x += r3.x; A3.y += r3.y; A3.z += r3.z; A3.w += r3.w;
    }
    for (; e < a1; e++) {
        int s = csr_src[e];
        uint2 q = *(const uint2*)&U[(size_t)s * 128 + l * 4];
        float4 r = unpack_bf16_quad(q);
        A0.x += r.x; A0.y += r.y; A0.z += r.z; A0.w += r.w;
    }

    float ax = (A0.x + A1.x) + (A2.x + A3.x);
    float ay = (A0.y + A1.y) + (A2.y + A3.y);
    float az = (A0.z + A1.z) + (A2.z + A3.z);
    float aw = (A0.w + A1.w) + (A2.w + A3.w);

    ax += __shfl_xor(ax, 32);
    ay += __shfl_xor(ay, 32);
    az += __shfl_xor(az, 32);
    aw += __shfl_xor(aw, 32);

    if (g == 0) {
        uint2 qs = *(const uint2*)&U[(size_t)n * 128 + l * 4];
        float4 self = unpack_bf16_quad(qs);
        float4 bi = *(const float4*)&bias[l * 4];
        float dn = dinv[n];
        float4 out;
        out.x = fmaxf(dn * (ax + self.x) + bi.x, 0.f);
        out.y = fmaxf(dn * (ay + self.y) + bi.y, 0.f);
        out.z = fmaxf(dn * (az + self.z) + bi.z, 0.f);
        out.w = fmaxf(dn * (aw + self.w) + bi.w, 0.f);
        if (RES) {
            float4 h = *(const float4*)&H[(size_t)n * 128 + l * 4];
            out.x += h.x; out.y += h.y; out.z += h.z; out.w += h.w;
        }
        *(float4*)&H[(size_t)n * 128 + l * 4] = out;
    }
}

// ---------------- pooling ----------------

__global__ __launch_bounds__(256) void k_gstart(const int* __restrict__ batch, int N, int G,
                                                int* __restrict__ gstart) {
    int g = blockIdx.x * 256 + threadIdx.x;
    if (g > G) return;
    if (g == G) { gstart[g] = N; return; }
    int lo = 0, hi = N;
    while (lo < hi) {
        int mid = (lo + hi) >> 1;
        if (batch[mid] < g) lo = mid + 1; else hi = mid;
    }
    gstart[g] = lo;
}

__global__ __launch_bounds__(256) void k_pool(const float* __restrict__ H,
                                              const int* __restrict__ gstart,
                                              float* __restrict__ gfeat) {
    __shared__ float ssum[256];
    __shared__ float smax[256];
    int g = blockIdx.x;
    int c = threadIdx.x & 127;
    int half = threadIdx.x >> 7;
    int i0 = gstart[g], i1 = gstart[g + 1];
    int cn = i1 - i0;
    int mid = i0 + (cn >> 1);
    int a0 = half ? mid : i0;
    int a1 = half ? i1 : mid;
    float s = 0.f, m = -3.4e38f;
    for (int i = a0; i < a1; i++) {
        float v = H[(size_t)i * 128 + c];
        s += v;
        m = fmaxf(m, v);
    }
    ssum[threadIdx.x] = s;
    smax[threadIdx.x] = m;
    __syncthreads();
    if (half == 0) {
        float st = ssum[c] + ssum[c + 128];
        float mt = fmaxf(smax[c], smax[c + 128]);
        float mean = (cn > 0) ? st / (float)cn : 0.f;
        if (cn == 0) mt = 0.f;
        gfeat[g * 256 + c] = mean;
        gfeat[g * 256 + 128 + c] = mt;
    }
}

// ---------------- MLP head ----------------

__global__ __launch_bounds__(128) void k_mlp(const float* __restrict__ gfeat,
                                             const float* __restrict__ Wf1,
                                             const float* __restrict__ bf1,
                                             const float* __restrict__ Wf2,
                                             const float* __restrict__ bf2,
                                             const float* __restrict__ Wf3,
                                             const float* __restrict__ bf3,
                                             float* __restrict__ out) {
    __shared__ float grow[256];
    __shared__ float o1[128];
    __shared__ float o2[64];
    int g = blockIdx.x;
    int t = threadIdx.x;
    grow[t] = gfeat[g * 256 + t];
    grow[t + 128] = gfeat[g * 256 + 128 + t];
    __syncthreads();
    float acc = bf1[t];
#pragma unroll 8
    for (int k = 0; k < 256; k++) acc = fmaf(grow[k], Wf1[k * 128 + t], acc);
    o1[t] = fmaxf(acc, 0.f);
    __syncthreads();
    if (t < 64) {
        float a2 = bf2[t];
#pragma unroll 8
        for (int k = 0; k < 128; k++) a2 = fmaf(o1[k], Wf2[k * 64 + t], a2);
        o2[t] = fmaxf(a2, 0.f);
    }
    __syncthreads();
    if (t < 64) {
        float p = o2[t] * Wf3[t];
        for (int off = 32; off > 0; off >>= 1) p += __shfl_down(p, off);
        if (t == 0) out[g] = p + bf3[0];
    }
}

// ---------------- launch ----------------

extern "C" void kernel_launch(void* const* d_in, const int* in_sizes, int n_in,
                              void* d_out, int out_size, void* d_ws, size_t ws_size,
                              hipStream_t stream) {
    const float* x = (const float*)d_in[0];
    const int* ei = (const int*)d_in[1];
    const int* batch = (const int*)d_in[2];
    const float* W1 = (const float*)d_in[4];
    const float* b1 = (const float*)d_in[5];
    const float* W2 = (const float*)d_in[6];
    const float* b2 = (const float*)d_in[7];
    const float* W3 = (const float*)d_in[8];
    const float* b3 = (const float*)d_in[9];
    const float* Wf1 = (const float*)d_in[10];
    const float* bf1 = (const float*)d_in[11];
    const float* Wf2 = (const float*)d_in[12];
    const float* bf2 = (const float*)d_in[13];
    const float* Wf3 = (const float*)d_in[14];
    const float* bf3 = (const float*)d_in[15];

    const int N = in_sizes[0] / 128;
    const int E = in_sizes[1] / 2;
    const int G = out_size;

    const int* src = ei;
    const int* dst = ei + E;

    char* w = (char*)d_ws;
    size_t off = 0;
    auto alloc = [&](size_t bytes) -> void* {
        void* p = w + off;
        off += (bytes + 255) / 256 * 256;
        return p;
    };
    unsigned short* U = (unsigned short*)alloc((size_t)N * 128 * 2);  // bf16 message table
    float* H = (float*)alloc((size_t)N * 128 * 4);
    uint2* pairs = (uint2*)alloc((size_t)E * 8);
    int* csr_src = (int*)alloc((size_t)E * 4);
    int* rowstart = (int*)alloc((size_t)(N + 1) * 4);
    int* cnt = (int*)alloc((size_t)N * 4);
    int* bcur = (int*)alloc(NBMAX * 4);
    float* dinv = (float*)alloc((size_t)N * 4);
    int* part = (int*)alloc(1024 * 4);
    int* boff = (int*)alloc(1024 * 4);
    int* gstart = (int*)alloc((size_t)(G + 1) * 4);
    float* gfeat = (float*)alloc((size_t)G * 256 * 4);
    unsigned short* WHb[3], *WLb[3];
    for (int i = 0; i < 3; i++) {
        WHb[i] = (unsigned short*)alloc(16384 * 2);
        WLb[i] = (unsigned short*)alloc(16384 * 2);
    }
    float* out = (float*)d_out;

    const int nblk = (N + 1023) / 1024;
    const int NB = (N + 1023) >> 10;

    hipMemsetAsync(cnt, 0, (size_t)N * 4, stream);

    // weight prep (tiny; L2-resident afterwards)
    k_wprep<<<dim3(64), dim3(256), 0, stream>>>(W1, WHb[0], WLb[0]);
    k_wprep<<<dim3(64), dim3(256), 0, stream>>>(W2, WHb[1], WLb[1]);
    k_wprep<<<dim3(64), dim3(256), 0, stream>>>(W3, WHb[2], WLb[2]);

    k_count<<<dim3((E + 255) / 256), dim3(256), 0, stream>>>(dst, E, cnt);
    k_scan1<<<dim3(nblk), dim3(256), 0, stream>>>(cnt, N, part);
    k_scan2<<<dim3(1), dim3(1024), 0, stream>>>(part, boff, nblk, rowstart, N, E);
    k_scan3<<<dim3(nblk), dim3(256), 0, stream>>>(cnt, N, boff, rowstart);
    k_dinv<<<dim3((N + 255) / 256), dim3(256), 0, stream>>>(cnt, dinv, N);
    k_binit<<<dim3((NB + 127) / 128), dim3(128), 0, stream>>>(rowstart, N, NB, bcur);
    k_bucket<<<dim3((E + 4095) / 4096), dim3(256), 0, stream>>>(src, dst, E, NB, bcur, pairs);
    k_place<<<dim3(NB), dim3(256), 0, stream>>>(pairs, rowstart, N, csr_src);

    const int gemmGrid = (N + 127) / 128;
    const int aggGrid = (N + 3) / 4;

    // conv1
    k_gemm3<<<dim3(gemmGrid), dim3(256), 0, stream>>>(x, WHb[0], WLb[0], dinv, U, N);
    k_agg<0><<<dim3(aggGrid), dim3(256), 0, stream>>>(U, rowstart, csr_src, dinv, b1, H, N);
    // conv2
    k_gemm3<<<dim3(gemmGrid), dim3(256), 0, stream>>>(H, WHb[1], WLb[1], dinv, U, N);
    k_agg<1><<<dim3(aggGrid), dim3(256), 0, stream>>>(U, rowstart, csr_src, dinv, b2, H, N);
    // conv3
    k_gemm3<<<dim3(gemmGrid), dim3(256), 0, stream>>>(H, WHb[2], WLb[2], dinv, U, N);
    k_agg<1><<<dim3(aggGrid), dim3(256), 0, stream>>>(U, rowstart, csr_src, dinv, b3, H, N);

    // pooling + head
    k_gstart<<<dim3((G + 256) / 256), dim3(256), 0, stream>>>(batch, N, G, gstart);
    k_pool<<<dim3(G), dim3(256), 0, stream>>>(H, gstart, gfeat);
    k_mlp<<<dim3(G), dim3(128), 0, stream>>>(gfeat, Wf1, bf1, Wf2, bf2, Wf3, bf3, out);
}

// Round 7
// 535.268 us; speedup vs baseline: 1.9661x; 1.1500x over previous
//
#include <hip/hip_runtime.h>
#include <hip/hip_bf16.h>

#define NBMAX 128   // max dst-buckets (N/1024); N=100K -> 98

typedef __attribute__((ext_vector_type(8))) short short8;   // 8 bf16 (4 VGPR) MFMA operand
typedef __attribute__((ext_vector_type(4))) float f32x4;    // MFMA accumulator

// ---- bf16 helpers (RNE) ----
__device__ inline unsigned short bf16_rne(float x) {
    unsigned u = __float_as_uint(x);
    u = (u + 0x7FFFu + ((u >> 16) & 1u)) >> 16;
    return (unsigned short)u;
}
__device__ inline float bf16_to_f(unsigned short h) {
    return __uint_as_float(((unsigned)h) << 16);
}
__device__ inline void split2(float v, short& h, short& lo) {
    unsigned short hb = bf16_rne(v);
    h = (short)hb;
    lo = (short)bf16_rne(v - bf16_to_f(hb));
}
__device__ inline float4 unpack_bf16_quad(uint2 q) {
    float4 r;
    r.x = __uint_as_float(q.x << 16);
    r.y = __uint_as_float(q.x & 0xFFFF0000u);
    r.z = __uint_as_float(q.y << 16);
    r.w = __uint_as_float(q.y & 0xFFFF0000u);
    return r;
}

// ---------------- preprocessing (bucket pipeline, no per-node device atomics) ----

// pass 0: per-bucket edge counts. LDS histogram -> ~NB global atomics per block.
__global__ __launch_bounds__(256) void k_bcnt(const int* __restrict__ dst, int E, int NB,
                                              int* __restrict__ bucket_cnt) {
    __shared__ int lcnt[NBMAX];
    int t = threadIdx.x;
    int base = blockIdx.x * 4096;
    for (int i = t; i < NB; i += 256) lcnt[i] = 0;
    __syncthreads();
#pragma unroll
    for (int i = 0; i < 16; i++) {
        int e = base + i * 256 + t;
        if (e < E) atomicAdd(&lcnt[dst[e] >> 10], 1);
    }
    __syncthreads();
    for (int i = t; i < NB; i += 256) {
        int c = lcnt[i];
        if (c) atomicAdd(&bucket_cnt[i], c);
    }
}

// scan of NB (<=128) bucket counts -> bucket_off, bcur; also rowstart[N]=E.
__global__ __launch_bounds__(128) void k_bscan(const int* __restrict__ bucket_cnt,
                                               int NB, int E, int N,
                                               int* __restrict__ bucket_off,
                                               int* __restrict__ bcur,
                                               int* __restrict__ rowstart) {
    __shared__ int sh[128];
    int t = threadIdx.x;
    int v = (t < NB) ? bucket_cnt[t] : 0;
    sh[t] = v;
    __syncthreads();
    for (int off = 1; off < 128; off <<= 1) {
        int x = (t >= off) ? sh[t - off] : 0;
        __syncthreads();
        sh[t] += x;
        __syncthreads();
    }
    if (t < NB) {
        int excl = sh[t] - v;
        bucket_off[t] = excl;
        bcur[t] = excl;
    }
    if (t == 0) {
        bucket_off[NB] = E;
        rowstart[N] = E;
    }
}

// pass 1: bucket-sort edges by dst>>10 into pairs[] (bucket-region-ordered).
__global__ __launch_bounds__(256) void k_bucket(const int* __restrict__ src,
                                                const int* __restrict__ dst, int E, int NB,
                                                int* __restrict__ bcur,
                                                uint2* __restrict__ pairs) {
    __shared__ int lcnt[NBMAX];
    __shared__ int gbase[NBMAX];
    int t = threadIdx.x;
    int base = blockIdx.x * 4096;
    for (int i = t; i < NB; i += 256) lcnt[i] = 0;
    __syncthreads();
    int rank[16];
#pragma unroll
    for (int i = 0; i < 16; i++) {
        int e = base + i * 256 + t;
        rank[i] = (e < E) ? atomicAdd(&lcnt[dst[e] >> 10], 1) : -1;
    }
    __syncthreads();
    for (int i = t; i < NB; i += 256) {
        int c = lcnt[i];
        gbase[i] = c ? atomicAdd(&bcur[i], c) : 0;
    }
    __syncthreads();
#pragma unroll
    for (int i = 0; i < 16; i++) {
        int e = base + i * 256 + t;
        if (e < E) {
            int d = dst[e];
            pairs[gbase[d >> 10] + rank[i]] = make_uint2((unsigned)src[e], (unsigned)d);
        }
    }
}

// pass 2: one block per bucket (1024 dst nodes). Fuses per-node count (LDS
// atomics), LDS scan -> rowstart + dinv, and cursor-based csr_src placement.
__global__ __launch_bounds__(1024) void k_node(const uint2* __restrict__ pairs,
                                               const int* __restrict__ bucket_off, int N,
                                               int* __restrict__ rowstart,
                                               float* __restrict__ dinv,
                                               int* __restrict__ csr_src) {
    __shared__ int cnt_l[1024];
    __shared__ int cur_l[1024];
    int t = threadIdx.x;
    int b = blockIdx.x;
    int n0 = b << 10;
    int nn = min(1024, N - n0);
    cnt_l[t] = 0;
    __syncthreads();
    int e0 = bucket_off[b], e1 = bucket_off[b + 1];
    for (int e = e0 + t; e < e1; e += 1024) {
        atomicAdd(&cnt_l[(int)pairs[e].y - n0], 1);
    }
    __syncthreads();
    int c = cnt_l[t];
    // inclusive scan (Hillis-Steele) over cnt_l
    for (int off = 1; off < 1024; off <<= 1) {
        int x = (t >= off) ? cnt_l[t - off] : 0;
        __syncthreads();
        cnt_l[t] += x;
        __syncthreads();
    }
    int start = e0 + cnt_l[t] - c;   // exclusive + bucket base
    cur_l[t] = start;
    if (t < nn) {
        rowstart[n0 + t] = start;
        dinv[n0 + t] = rsqrtf((float)c + 1.0f);  // deg = in-edges + self-loop
    }
    __syncthreads();
    for (int e = e0 + t; e < e1; e += 1024) {
        uint2 p = pairs[e];
        int r = atomicAdd(&cur_l[(int)p.y - n0], 1);
        csr_src[r] = (int)p.x;
    }
}

// ---------------- W prep: fragment-ordered bf16 hi/lo ----------------
// frag[((kc*8 + colTile)*64 + lane)*8 + j] = W[k=kc*32+(lane>>4)*8+j][col=colTile*16+(lane&15)]
__global__ __launch_bounds__(256) void k_wprep(const float* __restrict__ W,
                                               unsigned short* __restrict__ WH,
                                               unsigned short* __restrict__ WL) {
    int idx = blockIdx.x * 256 + threadIdx.x;  // 0..16383
    int j = idx & 7;
    int lane = (idx >> 3) & 63;
    int ct = (idx >> 9) & 7;
    int kc = idx >> 12;
    int k = kc * 32 + (lane >> 4) * 8 + j;
    int col = ct * 16 + (lane & 15);
    float v = W[k * 128 + col];
    unsigned short hb = bf16_rne(v);
    WH[idx] = hb;
    WL[idx] = bf16_rne(v - bf16_to_f(hb));
}

// ---------------- GEMM: U = bf16(dinv .* (A @ W)) via 3-term bf16 MFMA ----------
// A*W ~= Ah*Wh + Ah*Wl + Al*Wh; ~16 mantissa bits, error below bf16-U rounding.

__global__ __launch_bounds__(256) void k_gemm3(const float* __restrict__ A,
                                               const unsigned short* __restrict__ WH,
                                               const unsigned short* __restrict__ WL,
                                               const float* __restrict__ dinv,
                                               unsigned short* __restrict__ U, int N) {
    int wv = threadIdx.x >> 6;
    int l = threadIdx.x & 63;
    int quad = l >> 4;
    int lm = l & 15;
    int rowBase = blockIdx.x * 128 + wv * 32;

    f32x4 acc[2][8] = {};

    int r0 = rowBase + lm;        // rowTile 0: A[m=lane&15][k=quad*8+j]
    int r1 = rowBase + 16 + lm;   // rowTile 1

    for (int kc = 0; kc < 4; kc++) {
        int k0 = kc * 32 + quad * 8;
        float av0[8] = {}, av1[8] = {};
        if (r0 < N) {
            float4 a = *(const float4*)&A[(size_t)r0 * 128 + k0];
            float4 b = *(const float4*)&A[(size_t)r0 * 128 + k0 + 4];
            av0[0] = a.x; av0[1] = a.y; av0[2] = a.z; av0[3] = a.w;
            av0[4] = b.x; av0[5] = b.y; av0[6] = b.z; av0[7] = b.w;
        }
        if (r1 < N) {
            float4 a = *(const float4*)&A[(size_t)r1 * 128 + k0];
            float4 b = *(const float4*)&A[(size_t)r1 * 128 + k0 + 4];
            av1[0] = a.x; av1[1] = a.y; av1[2] = a.z; av1[3] = a.w;
            av1[4] = b.x; av1[5] = b.y; av1[6] = b.z; av1[7] = b.w;
        }
        short8 ah0, al0, ah1, al1;
#pragma unroll
        for (int j = 0; j < 8; j++) {
            short h, lo;
            split2(av0[j], h, lo); ah0[j] = h; al0[j] = lo;
            split2(av1[j], h, lo); ah1[j] = h; al1[j] = lo;
        }
#pragma unroll
        for (int ct = 0; ct < 8; ct++) {
            size_t fo = ((size_t)(kc * 8 + ct) * 64 + l) * 8;
            short8 wh = *(const short8*)&WH[fo];
            short8 wl = *(const short8*)&WL[fo];
            acc[0][ct] = __builtin_amdgcn_mfma_f32_16x16x32_bf16(ah0, wh, acc[0][ct], 0, 0, 0);
            acc[0][ct] = __builtin_amdgcn_mfma_f32_16x16x32_bf16(ah0, wl, acc[0][ct], 0, 0, 0);
            acc[0][ct] = __builtin_amdgcn_mfma_f32_16x16x32_bf16(al0, wh, acc[0][ct], 0, 0, 0);
            acc[1][ct] = __builtin_amdgcn_mfma_f32_16x16x32_bf16(ah1, wh, acc[1][ct], 0, 0, 0);
            acc[1][ct] = __builtin_amdgcn_mfma_f32_16x16x32_bf16(ah1, wl, acc[1][ct], 0, 0, 0);
            acc[1][ct] = __builtin_amdgcn_mfma_f32_16x16x32_bf16(al1, wh, acc[1][ct], 0, 0, 0);
        }
    }

    // epilogue: C/D map col=lane&15, row=quad*4+reg (m89-verified)
#pragma unroll
    for (int rt = 0; rt < 2; rt++) {
#pragma unroll
        for (int reg = 0; reg < 4; reg++) {
            int row = rowBase + rt * 16 + quad * 4 + reg;
            if (row < N) {
                float dv = dinv[row];
#pragma unroll
                for (int ct = 0; ct < 8; ct++) {
                    U[(size_t)row * 128 + ct * 16 + lm] = bf16_rne(dv * acc[rt][ct][reg]);
                }
            }
        }
    }
}

// ---------------- aggregation ----------------
// H[n] = relu(dinv[n] * (U[n] + sum_{e in CSR(n)} U[src_e]) + bias) (+ H[n] if RES)

template <int RES>
__global__ __launch_bounds__(256) void k_agg(const unsigned short* __restrict__ U,
                                             const int* __restrict__ rowstart,
                                             const int* __restrict__ csr_src,
                                             const float* __restrict__ dinv,
                                             const float* __restrict__ bias,
                                             float* __restrict__ H, int N) {
    int wave = threadIdx.x >> 6;  // 0..3
    int lane = threadIdx.x & 63;
    int n = blockIdx.x * 4 + wave;
    if (n >= N) return;
    int g = lane >> 5;   // edge group 0/1
    int l = lane & 31;   // channel quad: channels l*4 .. l*4+3
    int e0 = rowstart[n], e1 = rowstart[n + 1];
    int half = (e1 - e0) >> 1;
    int a0 = g ? (e0 + half) : e0;
    int a1 = g ? e1 : (e0 + half);

    float4 A0 = {0.f, 0.f, 0.f, 0.f};
    float4 A1 = {0.f, 0.f, 0.f, 0.f};
    float4 A2 = {0.f, 0.f, 0.f, 0.f};
    float4 A3 = {0.f, 0.f, 0.f, 0.f};

    int e = a0;
    for (; e + 4 <= a1; e += 4) {
        int s0 = csr_src[e], s1 = csr_src[e + 1];
        int s2 = csr_src[e + 2], s3 = csr_src[e + 3];
        uint2 q0 = *(const uint2*)&U[(size_t)s0 * 128 + l * 4];
        uint2 q1 = *(const uint2*)&U[(size_t)s1 * 128 + l * 4];
        uint2 q2 = *(const uint2*)&U[(size_t)s2 * 128 + l * 4];
        uint2 q3 = *(const uint2*)&U[(size_t)s3 * 128 + l * 4];
        float4 r0 = unpack_bf16_quad(q0);
        float4 r1 = unpack_bf16_quad(q1);
        float4 r2 = unpack_bf16_quad(q2);
        float4 r3 = unpack_bf16_quad(q3);
        A0.x += r0.x; A0.y += r0.y; A0.z += r0.z; A0.w += r0.w;
        A1.x += r1.x; A1.y += r1.y; A1.z += r1.z; A1.w += r1.w;
        A2.x += r2.x; A2.y += r2.y; A2.z += r2.z; A2.w += r2.w;
        A3.x += r3.x; A3.y += r3.y; A3.z += r3.z; A3.w += r3.w;
    }
    for (; e < a1; e++) {
        int s = csr_src[e];
        uint2 q = *(const uint2*)&U[(size_t)s * 128 + l * 4];
        float4 r = unpack_bf16_quad(q);
        A0.x += r.x; A0.y += r.y; A0.z += r.z; A0.w += r.w;
    }

    float ax = (A0.x + A1.x) + (A2.x + A3.x);
    float ay = (A0.y + A1.y) + (A2.y + A3.y);
    float az = (A0.z + A1.z) + (A2.z + A3.z);
    float aw = (A0.w + A1.w) + (A2.w + A3.w);

    ax += __shfl_xor(ax, 32);
    ay += __shfl_xor(ay, 32);
    az += __shfl_xor(az, 32);
    aw += __shfl_xor(aw, 32);

    if (g == 0) {
        uint2 qs = *(const uint2*)&U[(size_t)n * 128 + l * 4];
        float4 self = unpack_bf16_quad(qs);
        float4 bi = *(const float4*)&bias[l * 4];
        float dn = dinv[n];
        float4 out;
        out.x = fmaxf(dn * (ax + self.x) + bi.x, 0.f);
        out.y = fmaxf(dn * (ay + self.y) + bi.y, 0.f);
        out.z = fmaxf(dn * (az + self.z) + bi.z, 0.f);
        out.w = fmaxf(dn * (aw + self.w) + bi.w, 0.f);
        if (RES) {
            float4 h = *(const float4*)&H[(size_t)n * 128 + l * 4];
            out.x += h.x; out.y += h.y; out.z += h.z; out.w += h.w;
        }
        *(float4*)&H[(size_t)n * 128 + l * 4] = out;
    }
}

// ---------------- pooling ----------------

__global__ __launch_bounds__(256) void k_gstart(const int* __restrict__ batch, int N, int G,
                                                int* __restrict__ gstart) {
    int g = blockIdx.x * 256 + threadIdx.x;
    if (g > G) return;
    if (g == G) { gstart[g] = N; return; }
    int lo = 0, hi = N;
    while (lo < hi) {
        int mid = (lo + hi) >> 1;
        if (batch[mid] < g) lo = mid + 1; else hi = mid;
    }
    gstart[g] = lo;
}

__global__ __launch_bounds__(256) void k_pool(const float* __restrict__ H,
                                              const int* __restrict__ gstart,
                                              float* __restrict__ gfeat) {
    __shared__ float ssum[256];
    __shared__ float smax[256];
    int g = blockIdx.x;
    int c = threadIdx.x & 127;
    int half = threadIdx.x >> 7;
    int i0 = gstart[g], i1 = gstart[g + 1];
    int cn = i1 - i0;
    int mid = i0 + (cn >> 1);
    int a0 = half ? mid : i0;
    int a1 = half ? i1 : mid;
    float s = 0.f, m = -3.4e38f;
    for (int i = a0; i < a1; i++) {
        float v = H[(size_t)i * 128 + c];
        s += v;
        m = fmaxf(m, v);
    }
    ssum[threadIdx.x] = s;
    smax[threadIdx.x] = m;
    __syncthreads();
    if (half == 0) {
        float st = ssum[c] + ssum[c + 128];
        float mt = fmaxf(smax[c], smax[c + 128]);
        float mean = (cn > 0) ? st / (float)cn : 0.f;
        if (cn == 0) mt = 0.f;
        gfeat[g * 256 + c] = mean;
        gfeat[g * 256 + 128 + c] = mt;
    }
}

// ---------------- MLP head ----------------

__global__ __launch_bounds__(128) void k_mlp(const float* __restrict__ gfeat,
                                             const float* __restrict__ Wf1,
                                             const float* __restrict__ bf1,
                                             const float* __restrict__ Wf2,
                                             const float* __restrict__ bf2,
                                             const float* __restrict__ Wf3,
                                             const float* __restrict__ bf3,
                                             float* __restrict__ out) {
    __shared__ float grow[256];
    __shared__ float o1[128];
    __shared__ float o2[64];
    int g = blockIdx.x;
    int t = threadIdx.x;
    grow[t] = gfeat[g * 256 + t];
    grow[t + 128] = gfeat[g * 256 + 128 + t];
    __syncthreads();
    float acc = bf1[t];
#pragma unroll 8
    for (int k = 0; k < 256; k++) acc = fmaf(grow[k], Wf1[k * 128 + t], acc);
    o1[t] = fmaxf(acc, 0.f);
    __syncthreads();
    if (t < 64) {
        float a2 = bf2[t];
#pragma unroll 8
        for (int k = 0; k < 128; k++) a2 = fmaf(o1[k], Wf2[k * 64 + t], a2);
        o2[t] = fmaxf(a2, 0.f);
    }
    __syncthreads();
    if (t < 64) {
        float p = o2[t] * Wf3[t];
        for (int off = 32; off > 0; off >>= 1) p += __shfl_down(p, off);
        if (t == 0) out[g] = p + bf3[0];
    }
}

// ---------------- launch ----------------

extern "C" void kernel_launch(void* const* d_in, const int* in_sizes, int n_in,
                              void* d_out, int out_size, void* d_ws, size_t ws_size,
                              hipStream_t stream) {
    const float* x = (const float*)d_in[0];
    const int* ei = (const int*)d_in[1];
    const int* batch = (const int*)d_in[2];
    const float* W1 = (const float*)d_in[4];
    const float* b1 = (const float*)d_in[5];
    const float* W2 = (const float*)d_in[6];
    const float* b2 = (const float*)d_in[7];
    const float* W3 = (const float*)d_in[8];
    const float* b3 = (const float*)d_in[9];
    const float* Wf1 = (const float*)d_in[10];
    const float* bf1 = (const float*)d_in[11];
    const float* Wf2 = (const float*)d_in[12];
    const float* bf2 = (const float*)d_in[13];
    const float* Wf3 = (const float*)d_in[14];
    const float* bf3 = (const float*)d_in[15];

    const int N = in_sizes[0] / 128;
    const int E = in_sizes[1] / 2;
    const int G = out_size;

    const int* src = ei;
    const int* dst = ei + E;

    char* w = (char*)d_ws;
    size_t off = 0;
    auto alloc = [&](size_t bytes) -> void* {
        void* p = w + off;
        off += (bytes + 255) / 256 * 256;
        return p;
    };
    unsigned short* U = (unsigned short*)alloc((size_t)N * 128 * 2);  // bf16 message table
    float* H = (float*)alloc((size_t)N * 128 * 4);
    uint2* pairs = (uint2*)alloc((size_t)E * 8);
    int* csr_src = (int*)alloc((size_t)E * 4);
    int* rowstart = (int*)alloc((size_t)(N + 1) * 4);
    float* dinv = (float*)alloc((size_t)N * 4);
    int* bucket_cnt = (int*)alloc(NBMAX * 4);
    int* bucket_off = (int*)alloc((NBMAX + 1) * 4);
    int* bcur = (int*)alloc(NBMAX * 4);
    int* gstart = (int*)alloc((size_t)(G + 1) * 4);
    float* gfeat = (float*)alloc((size_t)G * 256 * 4);
    unsigned short* WHb[3], *WLb[3];
    for (int i = 0; i < 3; i++) {
        WHb[i] = (unsigned short*)alloc(16384 * 2);
        WLb[i] = (unsigned short*)alloc(16384 * 2);
    }
    float* out = (float*)d_out;

    const int NB = (N + 1023) >> 10;
    const int ebk = (E + 4095) / 4096;

    hipMemsetAsync(bucket_cnt, 0, NBMAX * 4, stream);

    // weight prep (tiny; L2-resident afterwards)
    k_wprep<<<dim3(64), dim3(256), 0, stream>>>(W1, WHb[0], WLb[0]);
    k_wprep<<<dim3(64), dim3(256), 0, stream>>>(W2, WHb[1], WLb[1]);
    k_wprep<<<dim3(64), dim3(256), 0, stream>>>(W3, WHb[2], WLb[2]);

    // CSR build: bucket pipeline
    k_bcnt<<<dim3(ebk), dim3(256), 0, stream>>>(dst, E, NB, bucket_cnt);
    k_bscan<<<dim3(1), dim3(128), 0, stream>>>(bucket_cnt, NB, E, N, bucket_off, bcur, rowstart);
    k_bucket<<<dim3(ebk), dim3(256), 0, stream>>>(src, dst, E, NB, bcur, pairs);
    k_node<<<dim3(NB), dim3(1024), 0, stream>>>(pairs, bucket_off, N, rowstart, dinv, csr_src);

    const int gemmGrid = (N + 127) / 128;
    const int aggGrid = (N + 3) / 4;

    // conv1
    k_gemm3<<<dim3(gemmGrid), dim3(256), 0, stream>>>(x, WHb[0], WLb[0], dinv, U, N);
    k_agg<0><<<dim3(aggGrid), dim3(256), 0, stream>>>(U, rowstart, csr_src, dinv, b1, H, N);
    // conv2
    k_gemm3<<<dim3(gemmGrid), dim3(256), 0, stream>>>(H, WHb[1], WLb[1], dinv, U, N);
    k_agg<1><<<dim3(aggGrid), dim3(256), 0, stream>>>(U, rowstart, csr_src, dinv, b2, H, N);
    // conv3
    k_gemm3<<<dim3(gemmGrid), dim3(256), 0, stream>>>(H, WHb[2], WLb[2], dinv, U, N);
    k_agg<1><<<dim3(aggGrid), dim3(256), 0, stream>>>(U, rowstart, csr_src, dinv, b3, H, N);

    // pooling + head
    k_gstart<<<dim3((G + 256) / 256), dim3(256), 0, stream>>>(batch, N, G, gstart);
    k_pool<<<dim3(G), dim3(256), 0, stream>>>(H, gstart, gfeat);
    k_mlp<<<dim3(G), dim3(128), 0, stream>>>(gfeat, Wf1, bf1, Wf2, bf2, Wf3, bf3, out);
}